// Round 1
// baseline (452.755 us; speedup 1.0000x reference)
//
#include <hip/hip_runtime.h>
#include <hip/hip_bf16.h>
#include <cstdint>

static constexpr int NN = 50000;   // nodes per graph
static constexpr int NE = 600000;  // edges per graph
static constexpr int NBLK = (NN + 255) / 256;  // 196 scan blocks (must be <= 256)

// ---------------- degree / dinv ----------------
__global__ __launch_bounds__(256) void k_count_deg(const int* __restrict__ dst,
                                                   int* __restrict__ deg, int e) {
    int i = blockIdx.x * 256 + threadIdx.x;
    if (i < e) atomicAdd(&deg[dst[i]], 1);
}

__global__ __launch_bounds__(256) void k_dinv(const int* __restrict__ deg,
                                              float* __restrict__ dinv, int n) {
    int i = blockIdx.x * 256 + threadIdx.x;
    if (i < n) dinv[i] = rsqrtf((float)deg[i] + 1.0f);
}

// ---------------- exclusive scan (3 kernels) ----------------
__global__ __launch_bounds__(256) void k_blocksum(const int* __restrict__ deg,
                                                  int* __restrict__ bsum, int n) {
    __shared__ int s[256];
    int tid = threadIdx.x;
    int i = blockIdx.x * 256 + tid;
    s[tid] = (i < n) ? deg[i] : 0;
    __syncthreads();
    for (int off = 128; off > 0; off >>= 1) {
        if (tid < off) s[tid] += s[tid + off];
        __syncthreads();
    }
    if (tid == 0) bsum[blockIdx.x] = s[0];
}

__global__ __launch_bounds__(256) void k_scan_aux(const int* __restrict__ bsum,
                                                  int* __restrict__ boff,
                                                  int* __restrict__ row_off, int nb, int n) {
    __shared__ int s[256];
    int tid = threadIdx.x;
    int v = (tid < nb) ? bsum[tid] : 0;
    s[tid] = v;
    __syncthreads();
    for (int off = 1; off < 256; off <<= 1) {
        int t = (tid >= off) ? s[tid - off] : 0;
        __syncthreads();
        s[tid] += t;
        __syncthreads();
    }
    if (tid < nb) boff[tid] = s[tid] - v;       // exclusive block offsets
    if (tid == nb - 1) row_off[n] = s[tid];     // total (= e)
}

__global__ __launch_bounds__(256) void k_scan_final(const int* __restrict__ deg,
                                                    const int* __restrict__ boff,
                                                    int* __restrict__ row_off, int n) {
    __shared__ int s[256];
    int tid = threadIdx.x;
    int i = blockIdx.x * 256 + tid;
    int v = (i < n) ? deg[i] : 0;
    s[tid] = v;
    __syncthreads();
    for (int off = 1; off < 256; off <<= 1) {
        int t = (tid >= off) ? s[tid - off] : 0;
        __syncthreads();
        s[tid] += t;
        __syncthreads();
    }
    if (i < n) row_off[i] = boff[blockIdx.x] + s[tid] - v;  // exclusive
}

__global__ __launch_bounds__(256) void k_fill(const int* __restrict__ src,
                                              const int* __restrict__ dst,
                                              const int* __restrict__ row_off,
                                              int* __restrict__ cursor,
                                              int* __restrict__ csr, int e) {
    int i = blockIdx.x * 256 + threadIdx.x;
    if (i < e) {
        int d = dst[i];
        int p = atomicAdd(&cursor[d], 1);
        csr[row_off[d] + p] = src[i];
    }
}

// ---------------- fp32 GEMM: H[n x F] = X[n x K] @ W[K x F] ----------------
template <int K, int F>
__global__ __launch_bounds__(256) void gemm_kernel(const float* __restrict__ X,
                                                   const float* __restrict__ W,
                                                   float* __restrict__ H, int n) {
    constexpr int BM = 64, BK = 32, TN = 4;
    constexpr int CT = F / TN;    // col-threads: 32 (F=128) or 16 (F=64)
    constexpr int RT = 256 / CT;  // row-threads: 8 or 16
    constexpr int TM = BM / RT;   // rows/thread: 8 or 4

    __shared__ float xs[BM][BK + 1];
    __shared__ float ws[BK][F];

    int tid = threadIdx.x;
    int ct = tid % CT;
    int rt = tid / CT;
    int r0 = blockIdx.x * BM;

    float acc[TM][TN] = {};

    for (int kb = 0; kb < K; kb += BK) {
        // stage X tile: 64 rows x 32 k (512 float4, 2/thread)
        #pragma unroll
        for (int l = 0; l < 2; ++l) {
            int idx = tid + l * 256;
            int row = idx / (BK / 4);
            int c4 = idx % (BK / 4);
            float4 v = make_float4(0.f, 0.f, 0.f, 0.f);
            int gr = r0 + row;
            if (gr < n) v = *reinterpret_cast<const float4*>(&X[(size_t)gr * K + kb + c4 * 4]);
            xs[row][c4 * 4 + 0] = v.x;
            xs[row][c4 * 4 + 1] = v.y;
            xs[row][c4 * 4 + 2] = v.z;
            xs[row][c4 * 4 + 3] = v.w;
        }
        // stage W tile: 32 k x F
        constexpr int WL = (BK * F / 4) / 256;
        #pragma unroll
        for (int l = 0; l < WL; ++l) {
            int idx = tid + l * 256;
            int row = idx / (F / 4);
            int c4 = idx % (F / 4);
            *reinterpret_cast<float4*>(&ws[row][c4 * 4]) =
                *reinterpret_cast<const float4*>(&W[(size_t)(kb + row) * F + c4 * 4]);
        }
        __syncthreads();
        #pragma unroll
        for (int kk = 0; kk < BK; ++kk) {
            float4 wv = *reinterpret_cast<const float4*>(&ws[kk][ct * TN]);
            #pragma unroll
            for (int m = 0; m < TM; ++m) {
                float xv = xs[rt * TM + m][kk];
                acc[m][0] = fmaf(xv, wv.x, acc[m][0]);
                acc[m][1] = fmaf(xv, wv.y, acc[m][1]);
                acc[m][2] = fmaf(xv, wv.z, acc[m][2]);
                acc[m][3] = fmaf(xv, wv.w, acc[m][3]);
            }
        }
        __syncthreads();
    }

    #pragma unroll
    for (int m = 0; m < TM; ++m) {
        int gr = r0 + rt * TM + m;
        if (gr < n) {
            float4 v = make_float4(acc[m][0], acc[m][1], acc[m][2], acc[m][3]);
            *reinterpret_cast<float4*>(&H[(size_t)gr * F + ct * TN]) = v;
        }
    }
}

// ---------------- aggregation: wave per node ----------------
// out[i] = bias + dinv_i^2 * h[i] + sum_{s in N(i)} dinv_s*dinv_i*h[s]   (+ReLU)
template <int F, bool RELU>
__global__ __launch_bounds__(256) void agg_kernel(const float* __restrict__ h,
                                                  const int* __restrict__ row_off,
                                                  const int* __restrict__ csr,
                                                  const float* __restrict__ dinv,
                                                  const float* __restrict__ bias,
                                                  float* __restrict__ out, int n) {
    constexpr int PER = F / 64;  // floats per lane: 2 (F=128) or 1 (F=64)
    int wid = blockIdx.x * 4 + (threadIdx.x >> 6);
    int lane = threadIdx.x & 63;
    if (wid >= n) return;

    float di = dinv[wid];
    int beg = row_off[wid];
    int end = row_off[wid + 1];

    float acc[PER];
    float selfc = di * di;
    #pragma unroll
    for (int p = 0; p < PER; ++p)
        acc[p] = h[(size_t)wid * F + p * 64 + lane] * selfc;

    int j = beg;
    for (; j + 1 < end; j += 2) {
        int s0 = csr[j];
        int s1 = csr[j + 1];
        float c0 = dinv[s0] * di;
        float c1 = dinv[s1] * di;
        #pragma unroll
        for (int p = 0; p < PER; ++p) {
            acc[p] += h[(size_t)s0 * F + p * 64 + lane] * c0;
            acc[p] += h[(size_t)s1 * F + p * 64 + lane] * c1;
        }
    }
    if (j < end) {
        int s = csr[j];
        float c = dinv[s] * di;
        #pragma unroll
        for (int p = 0; p < PER; ++p)
            acc[p] += h[(size_t)s * F + p * 64 + lane] * c;
    }

    #pragma unroll
    for (int p = 0; p < PER; ++p) {
        float v = acc[p] + bias[p * 64 + lane];
        if (RELU) v = fmaxf(v, 0.f);
        out[(size_t)wid * F + p * 64 + lane] = v;
    }
}

// ---------------- per-graph driver ----------------
static void run_gcn(const float* x, int K, const int* edges,
                    const float* W0, const float* b0,
                    const float* W1, const float* b1,
                    float* out,
                    float* h, float* a, int* csr, int* row_off, int* degcur,
                    float* dinv, int* bsum, int* boff, hipStream_t stream) {
    const int* src = edges;
    const int* dst = edges + NE;
    int* deg = degcur;
    int* cursor = degcur + NN;

    hipMemsetAsync(degcur, 0, 2 * (size_t)NN * sizeof(int), stream);
    k_count_deg<<<(NE + 255) / 256, 256, 0, stream>>>(dst, deg, NE);
    k_dinv<<<NBLK, 256, 0, stream>>>(deg, dinv, NN);
    k_blocksum<<<NBLK, 256, 0, stream>>>(deg, bsum, NN);
    k_scan_aux<<<1, 256, 0, stream>>>(bsum, boff, row_off, NBLK, NN);
    k_scan_final<<<NBLK, 256, 0, stream>>>(deg, boff, row_off, NN);
    k_fill<<<(NE + 255) / 256, 256, 0, stream>>>(src, dst, row_off, cursor, csr, NE);

    // layer 1: h = x @ W0 ; a = relu(agg(h) + b0)
    if (K == 256)
        gemm_kernel<256, 128><<<(NN + 63) / 64, 256, 0, stream>>>(x, W0, h, NN);
    else
        gemm_kernel<128, 128><<<(NN + 63) / 64, 256, 0, stream>>>(x, W0, h, NN);
    agg_kernel<128, true><<<(NN + 3) / 4, 256, 0, stream>>>(h, row_off, csr, dinv, b0, a, NN);

    // layer 2: h2 = a @ W1 (reuse h buffer) ; out = agg(h2) + b1
    gemm_kernel<128, 64><<<(NN + 63) / 64, 256, 0, stream>>>(a, W1, h, NN);
    agg_kernel<64, false><<<(NN + 3) / 4, 256, 0, stream>>>(h, row_off, csr, dinv, b1, out, NN);
}

extern "C" void kernel_launch(void* const* d_in, const int* in_sizes, int n_in,
                              void* d_out, int out_size, void* d_ws, size_t ws_size,
                              hipStream_t stream) {
    const float* x1 = (const float*)d_in[0];
    const int* ei1 = (const int*)d_in[1];
    const float* x2 = (const float*)d_in[2];
    const int* ei2 = (const int*)d_in[3];
    const float* W1_0 = (const float*)d_in[4];
    const float* b1_0 = (const float*)d_in[5];
    const float* W1_1 = (const float*)d_in[6];
    const float* b1_1 = (const float*)d_in[7];
    const float* W2_0 = (const float*)d_in[8];
    const float* b2_0 = (const float*)d_in[9];
    const float* W2_1 = (const float*)d_in[10];
    const float* b2_1 = (const float*)d_in[11];

    float* out = (float*)d_out;  // [2][NN][64] concatenated

    // workspace layout (reused across both graphs, processed sequentially)
    char* ws = (char*)d_ws;
    size_t off = 0;
    auto alloc = [&](size_t bytes) {
        size_t o = off;
        off = (off + bytes + 255) & ~(size_t)255;
        return o;
    };
    float* h = (float*)(ws + alloc((size_t)NN * 128 * 4));
    float* a = (float*)(ws + alloc((size_t)NN * 128 * 4));
    int* csr = (int*)(ws + alloc((size_t)NE * 4));
    int* row_off = (int*)(ws + alloc((size_t)(NN + 1) * 4));
    int* degcur = (int*)(ws + alloc((size_t)2 * NN * 4));  // deg | cursor (one memset)
    float* dinv = (float*)(ws + alloc((size_t)NN * 4));
    int* bsum = (int*)(ws + alloc(256 * 4));
    int* boff = (int*)(ws + alloc(256 * 4));

    run_gcn(x1, 256, ei1, W1_0, b1_0, W1_1, b1_1, out,
            h, a, csr, row_off, degcur, dinv, bsum, boff, stream);
    run_gcn(x2, 128, ei2, W2_0, b2_0, W2_1, b2_1, out + (size_t)NN * 64,
            h, a, csr, row_off, degcur, dinv, bsum, boff, stream);
}

// Round 2
// 391.830 us; speedup vs baseline: 1.1555x; 1.1555x over previous
//
#include <hip/hip_runtime.h>
#include <hip/hip_bf16.h>
#include <cstdint>

static constexpr int NN = 50000;   // nodes per graph
static constexpr int NE = 600000;  // edges per graph
static constexpr int NBLK = (NN + 255) / 256;  // 196 scan blocks (must be <= 256)

typedef __bf16 bf16;
typedef __attribute__((ext_vector_type(8))) __bf16 bf16x8;
typedef __attribute__((ext_vector_type(4))) float f32x4;

// ---------------- degree / dinv ----------------
__global__ __launch_bounds__(256) void k_count_deg(const int* __restrict__ dst,
                                                   int* __restrict__ deg, int e) {
    int i = blockIdx.x * 256 + threadIdx.x;
    if (i < e) atomicAdd(&deg[dst[i]], 1);
}

__global__ __launch_bounds__(256) void k_dinv(const int* __restrict__ deg,
                                              float* __restrict__ dinv, int n) {
    int i = blockIdx.x * 256 + threadIdx.x;
    if (i < n) dinv[i] = rsqrtf((float)deg[i] + 1.0f);
}

// ---------------- exclusive scan (3 kernels) ----------------
__global__ __launch_bounds__(256) void k_blocksum(const int* __restrict__ deg,
                                                  int* __restrict__ bsum, int n) {
    __shared__ int s[256];
    int tid = threadIdx.x;
    int i = blockIdx.x * 256 + tid;
    s[tid] = (i < n) ? deg[i] : 0;
    __syncthreads();
    for (int off = 128; off > 0; off >>= 1) {
        if (tid < off) s[tid] += s[tid + off];
        __syncthreads();
    }
    if (tid == 0) bsum[blockIdx.x] = s[0];
}

__global__ __launch_bounds__(256) void k_scan_aux(const int* __restrict__ bsum,
                                                  int* __restrict__ boff,
                                                  int* __restrict__ row_off, int nb, int n) {
    __shared__ int s[256];
    int tid = threadIdx.x;
    int v = (tid < nb) ? bsum[tid] : 0;
    s[tid] = v;
    __syncthreads();
    for (int off = 1; off < 256; off <<= 1) {
        int t = (tid >= off) ? s[tid - off] : 0;
        __syncthreads();
        s[tid] += t;
        __syncthreads();
    }
    if (tid < nb) boff[tid] = s[tid] - v;       // exclusive block offsets
    if (tid == nb - 1) row_off[n] = s[tid];     // total (= e)
}

__global__ __launch_bounds__(256) void k_scan_final(const int* __restrict__ deg,
                                                    const int* __restrict__ boff,
                                                    int* __restrict__ row_off, int n) {
    __shared__ int s[256];
    int tid = threadIdx.x;
    int i = blockIdx.x * 256 + tid;
    int v = (i < n) ? deg[i] : 0;
    s[tid] = v;
    __syncthreads();
    for (int off = 1; off < 256; off <<= 1) {
        int t = (tid >= off) ? s[tid - off] : 0;
        __syncthreads();
        s[tid] += t;
        __syncthreads();
    }
    if (i < n) row_off[i] = boff[blockIdx.x] + s[tid] - v;  // exclusive
}

__global__ __launch_bounds__(256) void k_fill(const int* __restrict__ src,
                                              const int* __restrict__ dst,
                                              const int* __restrict__ row_off,
                                              int* __restrict__ cursor,
                                              int* __restrict__ csr, int e) {
    int i = blockIdx.x * 256 + threadIdx.x;
    if (i < e) {
        int d = dst[i];
        int p = atomicAdd(&cursor[d], 1);
        csr[row_off[d] + p] = src[i];
    }
}

// ---------------- W prep: fp32 [K][F] -> fragment-order bf16 wf[k/8][n][8] ----------------
__global__ __launch_bounds__(256) void k_wprep(const float* __restrict__ W,
                                               bf16* __restrict__ wf, int K, int F) {
    int i = blockIdx.x * 256 + threadIdx.x;
    if (i < K * F) {
        int k = i / F, n = i % F;
        wf[((size_t)(k >> 3) * F + n) * 8 + (k & 7)] = (bf16)W[i];
    }
}

// ---------------- bf16 MFMA GEMM: H[n x F] = X[n x K] @ W[K x F] ----------------
// No LDS, no barriers. A loaded fp32->bf16 in-register; B from fragment-order wf.
// Fragment maps (16x16x32): A: m=l&15, k=(l>>4)*8+j ; B: n=l&15, k=(l>>4)*8+j ;
// D: n=l&15, m=(l>>4)*4+reg.
template <int K, int F>
__global__ __launch_bounds__(256) void gemm_mfma(const float* __restrict__ X,
                                                 const bf16* __restrict__ wf,
                                                 float* __restrict__ H, int n) {
    constexpr int NT = F / 16;  // 16x16 output tiles per wave (full N width)
    int wave = threadIdx.x >> 6;
    int lane = threadIdx.x & 63;
    int lm = lane & 15;   // m (A) / n (B) index
    int lk = lane >> 4;   // k-block index
    int r0 = blockIdx.x * 64 + wave * 16;

    int arow = r0 + lm;
    if (arow >= n) arow = n - 1;  // clamp (stores are guarded)
    const float* xrow = X + (size_t)arow * K;

    f32x4 acc[NT] = {};

    for (int k0 = 0; k0 < K; k0 += 32) {
        f32x4 a0 = *reinterpret_cast<const f32x4*>(xrow + k0 + lk * 8);
        f32x4 a1 = *reinterpret_cast<const f32x4*>(xrow + k0 + lk * 8 + 4);
        bf16x8 af;
        af[0] = (bf16)a0.x; af[1] = (bf16)a0.y; af[2] = (bf16)a0.z; af[3] = (bf16)a0.w;
        af[4] = (bf16)a1.x; af[5] = (bf16)a1.y; af[6] = (bf16)a1.z; af[7] = (bf16)a1.w;
        const bf16* wbase = wf + ((size_t)(k0 / 8 + lk) * F) * 8;
        #pragma unroll
        for (int t = 0; t < NT; ++t) {
            bf16x8 bfg = *reinterpret_cast<const bf16x8*>(wbase + (t * 16 + lm) * 8);
            acc[t] = __builtin_amdgcn_mfma_f32_16x16x32_bf16(af, bfg, acc[t], 0, 0, 0);
        }
    }

    #pragma unroll
    for (int t = 0; t < NT; ++t) {
        #pragma unroll
        for (int i = 0; i < 4; ++i) {
            int gr = r0 + lk * 4 + i;
            if (gr < n) H[(size_t)gr * F + t * 16 + lm] = acc[t][i];
        }
    }
}

// ---------------- aggregation: wave per node ----------------
// out[i] = bias + dinv_i^2 * h[i] + sum_{s in N(i)} dinv_s*dinv_i*h[s]   (+ReLU)
template <int F, bool RELU>
__global__ __launch_bounds__(256) void agg_kernel(const float* __restrict__ h,
                                                  const int* __restrict__ row_off,
                                                  const int* __restrict__ csr,
                                                  const float* __restrict__ dinv,
                                                  const float* __restrict__ bias,
                                                  float* __restrict__ out, int n) {
    constexpr int PER = F / 64;  // floats per lane: 2 (F=128) or 1 (F=64)
    int wid = blockIdx.x * 4 + (threadIdx.x >> 6);
    int lane = threadIdx.x & 63;
    if (wid >= n) return;

    float di = dinv[wid];
    int beg = row_off[wid];
    int end = row_off[wid + 1];

    float acc[PER];
    float selfc = di * di;
    #pragma unroll
    for (int p = 0; p < PER; ++p)
        acc[p] = h[(size_t)wid * F + p * 64 + lane] * selfc;

    int j = beg;
    for (; j + 1 < end; j += 2) {
        int s0 = csr[j];
        int s1 = csr[j + 1];
        float c0 = dinv[s0] * di;
        float c1 = dinv[s1] * di;
        #pragma unroll
        for (int p = 0; p < PER; ++p) {
            acc[p] += h[(size_t)s0 * F + p * 64 + lane] * c0;
            acc[p] += h[(size_t)s1 * F + p * 64 + lane] * c1;
        }
    }
    if (j < end) {
        int s = csr[j];
        float c = dinv[s] * di;
        #pragma unroll
        for (int p = 0; p < PER; ++p)
            acc[p] += h[(size_t)s * F + p * 64 + lane] * c;
    }

    #pragma unroll
    for (int p = 0; p < PER; ++p) {
        float v = acc[p] + bias[p * 64 + lane];
        if (RELU) v = fmaxf(v, 0.f);
        out[(size_t)wid * F + p * 64 + lane] = v;
    }
}

// ---------------- per-graph driver ----------------
static void run_gcn(const float* x, int K, const int* edges,
                    const float* W0, const float* b0,
                    const float* W1, const float* b1,
                    float* out,
                    float* h, float* a, int* csr, int* row_off, int* degcur,
                    float* dinv, int* bsum, int* boff,
                    bf16* wf0, bf16* wf1, hipStream_t stream) {
    const int* src = edges;
    const int* dst = edges + NE;
    int* deg = degcur;
    int* cursor = degcur + NN;

    hipMemsetAsync(degcur, 0, 2 * (size_t)NN * sizeof(int), stream);
    k_count_deg<<<(NE + 255) / 256, 256, 0, stream>>>(dst, deg, NE);
    k_dinv<<<NBLK, 256, 0, stream>>>(deg, dinv, NN);
    k_blocksum<<<NBLK, 256, 0, stream>>>(deg, bsum, NN);
    k_scan_aux<<<1, 256, 0, stream>>>(bsum, boff, row_off, NBLK, NN);
    k_scan_final<<<NBLK, 256, 0, stream>>>(deg, boff, row_off, NN);
    k_fill<<<(NE + 255) / 256, 256, 0, stream>>>(src, dst, row_off, cursor, csr, NE);

    // pack weights to fragment-order bf16
    k_wprep<<<(K * 128 + 255) / 256, 256, 0, stream>>>(W0, wf0, K, 128);
    k_wprep<<<(128 * 64 + 255) / 256, 256, 0, stream>>>(W1, wf1, 128, 64);

    // layer 1: h = x @ W0 ; a = relu(agg(h) + b0)
    if (K == 256)
        gemm_mfma<256, 128><<<(NN + 63) / 64, 256, 0, stream>>>(x, wf0, h, NN);
    else
        gemm_mfma<128, 128><<<(NN + 63) / 64, 256, 0, stream>>>(x, wf0, h, NN);
    agg_kernel<128, true><<<(NN + 3) / 4, 256, 0, stream>>>(h, row_off, csr, dinv, b0, a, NN);

    // layer 2: h2 = a @ W1 (reuse h buffer) ; out = agg(h2) + b1
    gemm_mfma<128, 64><<<(NN + 63) / 64, 256, 0, stream>>>(a, wf1, h, NN);
    agg_kernel<64, false><<<(NN + 3) / 4, 256, 0, stream>>>(h, row_off, csr, dinv, b1, out, NN);
}

extern "C" void kernel_launch(void* const* d_in, const int* in_sizes, int n_in,
                              void* d_out, int out_size, void* d_ws, size_t ws_size,
                              hipStream_t stream) {
    const float* x1 = (const float*)d_in[0];
    const int* ei1 = (const int*)d_in[1];
    const float* x2 = (const float*)d_in[2];
    const int* ei2 = (const int*)d_in[3];
    const float* W1_0 = (const float*)d_in[4];
    const float* b1_0 = (const float*)d_in[5];
    const float* W1_1 = (const float*)d_in[6];
    const float* b1_1 = (const float*)d_in[7];
    const float* W2_0 = (const float*)d_in[8];
    const float* b2_0 = (const float*)d_in[9];
    const float* W2_1 = (const float*)d_in[10];
    const float* b2_1 = (const float*)d_in[11];

    float* out = (float*)d_out;  // [2][NN][64] concatenated

    // workspace layout (reused across both graphs, processed sequentially)
    char* ws = (char*)d_ws;
    size_t off = 0;
    auto alloc = [&](size_t bytes) {
        size_t o = off;
        off = (off + bytes + 255) & ~(size_t)255;
        return o;
    };
    float* h = (float*)(ws + alloc((size_t)NN * 128 * 4));
    float* a = (float*)(ws + alloc((size_t)NN * 128 * 4));
    int* csr = (int*)(ws + alloc((size_t)NE * 4));
    int* row_off = (int*)(ws + alloc((size_t)(NN + 1) * 4));
    int* degcur = (int*)(ws + alloc((size_t)2 * NN * 4));  // deg | cursor (one memset)
    float* dinv = (float*)(ws + alloc((size_t)NN * 4));
    int* bsum = (int*)(ws + alloc(256 * 4));
    int* boff = (int*)(ws + alloc(256 * 4));
    bf16* wf0 = (bf16*)(ws + alloc((size_t)256 * 128 * 2));  // max K x F
    bf16* wf1 = (bf16*)(ws + alloc((size_t)128 * 64 * 2));

    run_gcn(x1, 256, ei1, W1_0, b1_0, W1_1, b1_1, out,
            h, a, csr, row_off, degcur, dinv, bsum, boff, wf0, wf1, stream);
    run_gcn(x2, 128, ei2, W2_0, b2_0, W2_1, b2_1, out + (size_t)NN * 64,
            h, a, csr, row_off, degcur, dinv, bsum, boff, wf0, wf1, stream);
}

// Round 3
// 338.596 us; speedup vs baseline: 1.3372x; 1.1572x over previous
//
#include <hip/hip_runtime.h>
#include <hip/hip_bf16.h>
#include <cstdint>
#include <type_traits>

static constexpr int NN = 50000;   // nodes per graph
static constexpr int NE = 600000;  // edges per graph
static constexpr int NBLK = (NN + 255) / 256;  // 196 scan blocks (must be <= 256)

typedef __bf16 bf16;
typedef __attribute__((ext_vector_type(2))) __bf16 bf16x2;
typedef __attribute__((ext_vector_type(8))) __bf16 bf16x8;
typedef __attribute__((ext_vector_type(4))) float f32x4;

// ---------------- degree / dinv ----------------
__global__ __launch_bounds__(256) void k_count_deg(const int* __restrict__ dst,
                                                   int* __restrict__ deg, int e) {
    int i = blockIdx.x * 256 + threadIdx.x;
    if (i < e) atomicAdd(&deg[dst[i]], 1);
}

__global__ __launch_bounds__(256) void k_dinv(const int* __restrict__ deg,
                                              float* __restrict__ dinv, int n) {
    int i = blockIdx.x * 256 + threadIdx.x;
    if (i < n) dinv[i] = rsqrtf((float)deg[i] + 1.0f);
}

// ---------------- exclusive scan (3 kernels) ----------------
__global__ __launch_bounds__(256) void k_blocksum(const int* __restrict__ deg,
                                                  int* __restrict__ bsum, int n) {
    __shared__ int s[256];
    int tid = threadIdx.x;
    int i = blockIdx.x * 256 + tid;
    s[tid] = (i < n) ? deg[i] : 0;
    __syncthreads();
    for (int off = 128; off > 0; off >>= 1) {
        if (tid < off) s[tid] += s[tid + off];
        __syncthreads();
    }
    if (tid == 0) bsum[blockIdx.x] = s[0];
}

__global__ __launch_bounds__(256) void k_scan_aux(const int* __restrict__ bsum,
                                                  int* __restrict__ boff,
                                                  int* __restrict__ row_off, int nb, int n) {
    __shared__ int s[256];
    int tid = threadIdx.x;
    int v = (tid < nb) ? bsum[tid] : 0;
    s[tid] = v;
    __syncthreads();
    for (int off = 1; off < 256; off <<= 1) {
        int t = (tid >= off) ? s[tid - off] : 0;
        __syncthreads();
        s[tid] += t;
        __syncthreads();
    }
    if (tid < nb) boff[tid] = s[tid] - v;       // exclusive block offsets
    if (tid == nb - 1) row_off[n] = s[tid];     // total (= e)
}

__global__ __launch_bounds__(256) void k_scan_final(const int* __restrict__ deg,
                                                    const int* __restrict__ boff,
                                                    int* __restrict__ row_off, int n) {
    __shared__ int s[256];
    int tid = threadIdx.x;
    int i = blockIdx.x * 256 + tid;
    int v = (i < n) ? deg[i] : 0;
    s[tid] = v;
    __syncthreads();
    for (int off = 1; off < 256; off <<= 1) {
        int t = (tid >= off) ? s[tid - off] : 0;
        __syncthreads();
        s[tid] += t;
        __syncthreads();
    }
    if (i < n) row_off[i] = boff[blockIdx.x] + s[tid] - v;  // exclusive
}

// fill CSR (src index) + per-edge coefficient dinv[src]*dinv[dst]
__global__ __launch_bounds__(256) void k_fill(const int* __restrict__ src,
                                              const int* __restrict__ dst,
                                              const int* __restrict__ row_off,
                                              int* __restrict__ cursor,
                                              const float* __restrict__ dinv,
                                              int* __restrict__ csr,
                                              float* __restrict__ coef, int e) {
    int i = blockIdx.x * 256 + threadIdx.x;
    if (i < e) {
        int d = dst[i];
        int s = src[i];
        int p = atomicAdd(&cursor[d], 1);
        int pos = row_off[d] + p;
        csr[pos] = s;
        coef[pos] = dinv[s] * dinv[d];
    }
}

// ---------------- W prep: fp32 [K][F] -> fragment-order bf16 wf[k/8][n][8] ----------------
__global__ __launch_bounds__(256) void k_wprep(const float* __restrict__ W,
                                               bf16* __restrict__ wf, int K, int F) {
    int i = blockIdx.x * 256 + threadIdx.x;
    if (i < K * F) {
        int k = i / F, n = i % F;
        wf[((size_t)(k >> 3) * F + n) * 8 + (k & 7)] = (bf16)W[i];
    }
}

// ---------------- bf16 MFMA GEMM: H[n x F] = X[n x K] @ W[K x F], H in bf16 ----------------
// No LDS, no barriers. A loaded (fp32->bf16 in-register, or bf16 direct);
// B from fragment-order wf. Fragment maps (16x16x32):
// A: m=l&15, k=(l>>4)*8+j ; B: n=l&15, k=(l>>4)*8+j ; D: n=l&15, m=(l>>4)*4+reg.
template <int K, int F, typename AT>
__global__ __launch_bounds__(256) void gemm_mfma(const AT* __restrict__ X,
                                                 const bf16* __restrict__ wf,
                                                 bf16* __restrict__ H, int n) {
    constexpr int NT = F / 16;  // 16x16 output tiles per wave (full N width)
    int wave = threadIdx.x >> 6;
    int lane = threadIdx.x & 63;
    int lm = lane & 15;   // m (A) / n (B) index
    int lk = lane >> 4;   // k-block index
    int r0 = blockIdx.x * 64 + wave * 16;

    int arow = r0 + lm;
    if (arow >= n) arow = n - 1;  // clamp (stores are guarded)
    const AT* xrow = X + (size_t)arow * K;

    f32x4 acc[NT] = {};

    for (int k0 = 0; k0 < K; k0 += 32) {
        bf16x8 af;
        if constexpr (std::is_same_v<AT, float>) {
            f32x4 a0 = *reinterpret_cast<const f32x4*>(xrow + k0 + lk * 8);
            f32x4 a1 = *reinterpret_cast<const f32x4*>(xrow + k0 + lk * 8 + 4);
            af[0] = (bf16)a0.x; af[1] = (bf16)a0.y; af[2] = (bf16)a0.z; af[3] = (bf16)a0.w;
            af[4] = (bf16)a1.x; af[5] = (bf16)a1.y; af[6] = (bf16)a1.z; af[7] = (bf16)a1.w;
        } else {
            af = *reinterpret_cast<const bf16x8*>(xrow + k0 + lk * 8);
        }
        const bf16* wbase = wf + ((size_t)(k0 / 8 + lk) * F) * 8;
        #pragma unroll
        for (int t = 0; t < NT; ++t) {
            bf16x8 bfg = *reinterpret_cast<const bf16x8*>(wbase + (t * 16 + lm) * 8);
            acc[t] = __builtin_amdgcn_mfma_f32_16x16x32_bf16(af, bfg, acc[t], 0, 0, 0);
        }
    }

    #pragma unroll
    for (int t = 0; t < NT; ++t) {
        #pragma unroll
        for (int i = 0; i < 4; ++i) {
            int gr = r0 + lk * 4 + i;
            if (gr < n) H[(size_t)gr * F + t * 16 + lm] = (bf16)acc[t][i];
        }
    }
}

// ---------------- aggregation F=128: wave per node, bf16 in, bf16 out, ReLU ----------------
// a[i] = relu(bias + dinv_i^2 * h[i] + sum_{s in N(i)} coef * h[s])
__global__ __launch_bounds__(256) void agg128(const bf16* __restrict__ h,
                                              const int* __restrict__ row_off,
                                              const int* __restrict__ csr,
                                              const float* __restrict__ coef,
                                              const float* __restrict__ dinv,
                                              const float* __restrict__ bias,
                                              bf16* __restrict__ a, int n) {
    int wid = blockIdx.x * 4 + (threadIdx.x >> 6);
    int lane = threadIdx.x & 63;
    if (wid >= n) return;

    int f = lane * 2;
    float di = dinv[wid];
    int beg = row_off[wid];
    int end = row_off[wid + 1];

    float a0 = 0.f, a1 = 0.f;

    int j = beg;
    for (; j + 3 < end; j += 4) {
        int s0 = csr[j], s1 = csr[j + 1], s2 = csr[j + 2], s3 = csr[j + 3];
        float c0 = coef[j], c1 = coef[j + 1], c2 = coef[j + 2], c3 = coef[j + 3];
        bf16x2 v0 = *reinterpret_cast<const bf16x2*>(&h[(size_t)s0 * 128 + f]);
        bf16x2 v1 = *reinterpret_cast<const bf16x2*>(&h[(size_t)s1 * 128 + f]);
        bf16x2 v2 = *reinterpret_cast<const bf16x2*>(&h[(size_t)s2 * 128 + f]);
        bf16x2 v3 = *reinterpret_cast<const bf16x2*>(&h[(size_t)s3 * 128 + f]);
        a0 = fmaf((float)v0[0], c0, a0); a1 = fmaf((float)v0[1], c0, a1);
        a0 = fmaf((float)v1[0], c1, a0); a1 = fmaf((float)v1[1], c1, a1);
        a0 = fmaf((float)v2[0], c2, a0); a1 = fmaf((float)v2[1], c2, a1);
        a0 = fmaf((float)v3[0], c3, a0); a1 = fmaf((float)v3[1], c3, a1);
    }
    for (; j < end; ++j) {
        int s = csr[j];
        float c = coef[j];
        bf16x2 v = *reinterpret_cast<const bf16x2*>(&h[(size_t)s * 128 + f]);
        a0 = fmaf((float)v[0], c, a0); a1 = fmaf((float)v[1], c, a1);
    }

    // self term + bias
    bf16x2 hv = *reinterpret_cast<const bf16x2*>(&h[(size_t)wid * 128 + f]);
    float sc = di * di;
    a0 = fmaf((float)hv[0], sc, a0) + bias[f];
    a1 = fmaf((float)hv[1], sc, a1) + bias[f + 1];
    a0 = fmaxf(a0, 0.f);
    a1 = fmaxf(a1, 0.f);

    bf16x2 r;
    r[0] = (bf16)a0; r[1] = (bf16)a1;
    *reinterpret_cast<bf16x2*>(&a[(size_t)wid * 128 + f]) = r;
}

// ---------------- aggregation F=64: wave per node, 2 edges/iter, fp32 out ----------------
__global__ __launch_bounds__(256) void agg64(const bf16* __restrict__ h,
                                             const int* __restrict__ row_off,
                                             const int* __restrict__ csr,
                                             const float* __restrict__ coef,
                                             const float* __restrict__ dinv,
                                             const float* __restrict__ bias,
                                             float* __restrict__ out, int n) {
    int wid = blockIdx.x * 4 + (threadIdx.x >> 6);
    int lane = threadIdx.x & 63;
    if (wid >= n) return;

    int half = lane >> 5;        // which edge of the pair
    int f = (lane & 31) * 2;     // feature base
    float di = dinv[wid];
    int beg = row_off[wid];
    int end = row_off[wid + 1];

    float a0 = 0.f, a1 = 0.f;

    int j = beg;
    for (; j + 3 < end; j += 4) {
        int sA = csr[j + half], sB = csr[j + 2 + half];
        float cA = coef[j + half], cB = coef[j + 2 + half];
        bf16x2 vA = *reinterpret_cast<const bf16x2*>(&h[(size_t)sA * 64 + f]);
        bf16x2 vB = *reinterpret_cast<const bf16x2*>(&h[(size_t)sB * 64 + f]);
        a0 = fmaf((float)vA[0], cA, a0); a1 = fmaf((float)vA[1], cA, a1);
        a0 = fmaf((float)vB[0], cB, a0); a1 = fmaf((float)vB[1], cB, a1);
    }
    for (; j + 1 < end; j += 2) {
        int s = csr[j + half];
        float c = coef[j + half];
        bf16x2 v = *reinterpret_cast<const bf16x2*>(&h[(size_t)s * 64 + f]);
        a0 = fmaf((float)v[0], c, a0); a1 = fmaf((float)v[1], c, a1);
    }
    if (j < end && half == 0) {
        int s = csr[j];
        float c = coef[j];
        bf16x2 v = *reinterpret_cast<const bf16x2*>(&h[(size_t)s * 64 + f]);
        a0 = fmaf((float)v[0], c, a0); a1 = fmaf((float)v[1], c, a1);
    }

    // reduce the two halves
    a0 += __shfl_xor(a0, 32);
    a1 += __shfl_xor(a1, 32);

    // self term + bias (single time, post-reduce)
    bf16x2 hv = *reinterpret_cast<const bf16x2*>(&h[(size_t)wid * 64 + f]);
    float sc = di * di;
    a0 = fmaf((float)hv[0], sc, a0) + bias[f];
    a1 = fmaf((float)hv[1], sc, a1) + bias[f + 1];

    if (half == 0) {
        out[(size_t)wid * 64 + f] = a0;
        out[(size_t)wid * 64 + f + 1] = a1;
    }
}

// ---------------- per-graph driver ----------------
static void run_gcn(const float* x, int K, const int* edges,
                    const float* W0, const float* b0,
                    const float* W1, const float* b1,
                    float* out,
                    bf16* h, bf16* a, int* csr, float* coef, int* row_off,
                    int* degcur, float* dinv, int* bsum, int* boff,
                    bf16* wf0, bf16* wf1, hipStream_t stream) {
    const int* src = edges;
    const int* dst = edges + NE;
    int* deg = degcur;
    int* cursor = degcur + NN;

    hipMemsetAsync(degcur, 0, 2 * (size_t)NN * sizeof(int), stream);
    k_count_deg<<<(NE + 255) / 256, 256, 0, stream>>>(dst, deg, NE);
    k_dinv<<<NBLK, 256, 0, stream>>>(deg, dinv, NN);
    k_blocksum<<<NBLK, 256, 0, stream>>>(deg, bsum, NN);
    k_scan_aux<<<1, 256, 0, stream>>>(bsum, boff, row_off, NBLK, NN);
    k_scan_final<<<NBLK, 256, 0, stream>>>(deg, boff, row_off, NN);
    k_fill<<<(NE + 255) / 256, 256, 0, stream>>>(src, dst, row_off, cursor, dinv, csr, coef, NE);

    // pack weights to fragment-order bf16
    k_wprep<<<(K * 128 + 255) / 256, 256, 0, stream>>>(W0, wf0, K, 128);
    k_wprep<<<(128 * 64 + 255) / 256, 256, 0, stream>>>(W1, wf1, 128, 64);

    // layer 1: h = x @ W0 ; a = relu(agg(h) + b0)
    if (K == 256)
        gemm_mfma<256, 128, float><<<(NN + 63) / 64, 256, 0, stream>>>(x, wf0, h, NN);
    else
        gemm_mfma<128, 128, float><<<(NN + 63) / 64, 256, 0, stream>>>(x, wf0, h, NN);
    agg128<<<(NN + 3) / 4, 256, 0, stream>>>(h, row_off, csr, coef, dinv, b0, a, NN);

    // layer 2: h2 = a @ W1 (reuse h buffer) ; out = agg(h2) + b1
    gemm_mfma<128, 64, bf16><<<(NN + 63) / 64, 256, 0, stream>>>(a, wf1, h, NN);
    agg64<<<(NN + 3) / 4, 256, 0, stream>>>(h, row_off, csr, coef, dinv, b1, out, NN);
}

extern "C" void kernel_launch(void* const* d_in, const int* in_sizes, int n_in,
                              void* d_out, int out_size, void* d_ws, size_t ws_size,
                              hipStream_t stream) {
    const float* x1 = (const float*)d_in[0];
    const int* ei1 = (const int*)d_in[1];
    const float* x2 = (const float*)d_in[2];
    const int* ei2 = (const int*)d_in[3];
    const float* W1_0 = (const float*)d_in[4];
    const float* b1_0 = (const float*)d_in[5];
    const float* W1_1 = (const float*)d_in[6];
    const float* b1_1 = (const float*)d_in[7];
    const float* W2_0 = (const float*)d_in[8];
    const float* b2_0 = (const float*)d_in[9];
    const float* W2_1 = (const float*)d_in[10];
    const float* b2_1 = (const float*)d_in[11];

    float* out = (float*)d_out;  // [2][NN][64] concatenated

    // workspace layout (reused across both graphs, processed sequentially)
    char* ws = (char*)d_ws;
    size_t off = 0;
    auto alloc = [&](size_t bytes) {
        size_t o = off;
        off = (off + bytes + 255) & ~(size_t)255;
        return o;
    };
    bf16* h = (bf16*)(ws + alloc((size_t)NN * 128 * 2));
    bf16* a = (bf16*)(ws + alloc((size_t)NN * 128 * 2));
    int* csr = (int*)(ws + alloc((size_t)NE * 4));
    float* coef = (float*)(ws + alloc((size_t)NE * 4));
    int* row_off = (int*)(ws + alloc((size_t)(NN + 1) * 4));
    int* degcur = (int*)(ws + alloc((size_t)2 * NN * 4));  // deg | cursor (one memset)
    float* dinv = (float*)(ws + alloc((size_t)NN * 4));
    int* bsum = (int*)(ws + alloc(256 * 4));
    int* boff = (int*)(ws + alloc(256 * 4));
    bf16* wf0 = (bf16*)(ws + alloc((size_t)256 * 128 * 2));  // max K x F
    bf16* wf1 = (bf16*)(ws + alloc((size_t)128 * 64 * 2));

    run_gcn(x1, 256, ei1, W1_0, b1_0, W1_1, b1_1, out,
            h, a, csr, coef, row_off, degcur, dinv, bsum, boff, wf0, wf1, stream);
    run_gcn(x2, 128, ei2, W2_0, b2_0, W2_1, b2_1, out + (size_t)NN * 64,
            h, a, csr, coef, row_off, degcur, dinv, bsum, boff, wf0, wf1, stream);
}

// Round 4
// 287.509 us; speedup vs baseline: 1.5748x; 1.1777x over previous
//
#include <hip/hip_runtime.h>
#include <hip/hip_bf16.h>
#include <cstdint>
#include <type_traits>

static constexpr int NN = 50000;   // nodes per graph
static constexpr int NE = 600000;  // edges per graph
static constexpr int NBLK = (NN + 255) / 256;  // 196 scan blocks per graph (<= 256)

typedef __bf16 bf16;
typedef __attribute__((ext_vector_type(2))) __bf16 bf16x2;
typedef __attribute__((ext_vector_type(8))) __bf16 bf16x8;
typedef __attribute__((ext_vector_type(4))) float f32x4;

// ---------------- degree count, both graphs ----------------
__global__ __launch_bounds__(256) void k_count_deg2(const int* __restrict__ dstA,
                                                    const int* __restrict__ dstB,
                                                    int* __restrict__ deg) {
    int i = blockIdx.x * 256 + threadIdx.x;
    if (i < NE) atomicAdd(&deg[dstA[i]], 1);
    else if (i < 2 * NE) atomicAdd(&deg[NN + dstB[i - NE]], 1);
}

// ---------------- exclusive scan (3 kernels), both graphs via grid.y ----------------
__global__ __launch_bounds__(256) void k_blocksum2(const int* __restrict__ deg,
                                                   int* __restrict__ bsum) {
    __shared__ int s[256];
    int g = blockIdx.y;
    int tid = threadIdx.x;
    int i = blockIdx.x * 256 + tid;
    s[tid] = (i < NN) ? deg[g * NN + i] : 0;
    __syncthreads();
    for (int off = 128; off > 0; off >>= 1) {
        if (tid < off) s[tid] += s[tid + off];
        __syncthreads();
    }
    if (tid == 0) bsum[g * NBLK + blockIdx.x] = s[0];
}

__global__ __launch_bounds__(256) void k_scan_aux2(const int* __restrict__ bsum,
                                                   int* __restrict__ boff,
                                                   int* __restrict__ row_off) {
    __shared__ int s[256];
    int g = blockIdx.x;
    int tid = threadIdx.x;
    int v = (tid < NBLK) ? bsum[g * NBLK + tid] : 0;
    s[tid] = v;
    __syncthreads();
    for (int off = 1; off < 256; off <<= 1) {
        int t = (tid >= off) ? s[tid - off] : 0;
        __syncthreads();
        s[tid] += t;
        __syncthreads();
    }
    if (tid < NBLK) boff[g * NBLK + tid] = s[tid] - v;           // exclusive block offsets
    if (tid == NBLK - 1) row_off[g * (NN + 1) + NN] = s[tid];    // total (= NE)
}

// also writes poscur (cursor pre-initialized to row start) and dinv
__global__ __launch_bounds__(256) void k_scan_final2(const int* __restrict__ deg,
                                                     const int* __restrict__ boff,
                                                     int* __restrict__ row_off,
                                                     int* __restrict__ poscur,
                                                     float* __restrict__ dinv) {
    __shared__ int s[256];
    int g = blockIdx.y;
    int tid = threadIdx.x;
    int i = blockIdx.x * 256 + tid;
    int v = (i < NN) ? deg[g * NN + i] : 0;
    s[tid] = v;
    __syncthreads();
    for (int off = 1; off < 256; off <<= 1) {
        int t = (tid >= off) ? s[tid - off] : 0;
        __syncthreads();
        s[tid] += t;
        __syncthreads();
    }
    if (i < NN) {
        int excl = boff[g * NBLK + blockIdx.x] + s[tid] - v;
        row_off[g * (NN + 1) + i] = excl;
        poscur[g * NN + i] = excl;
        dinv[g * NN + i] = rsqrtf((float)v + 1.0f);
    }
}

// ---------------- CSR fill: pair {src, coef} in one 8B store, both graphs ----------------
__global__ __launch_bounds__(256) void k_fill2(const int* __restrict__ srcA,
                                               const int* __restrict__ dstA,
                                               const int* __restrict__ srcB,
                                               const int* __restrict__ dstB,
                                               int* __restrict__ poscur,
                                               const float* __restrict__ dinv,
                                               int2* __restrict__ pair) {
    int i = blockIdx.x * 256 + threadIdx.x;
    if (i >= 2 * NE) return;
    int g = (i >= NE);
    int e = i - g * NE;
    int s = g ? srcB[e] : srcA[e];
    int d = g ? dstB[e] : dstA[e];
    const float* dv = dinv + g * NN;
    int pos = atomicAdd(&poscur[g * NN + d], 1);
    int2 p;
    p.x = s;
    p.y = __float_as_int(dv[s] * dv[d]);
    pair[g * NE + pos] = p;
}

// ---------------- W prep: fp32 [K][F] -> fragment-order bf16 wf[k/8][n][8], 4 jobs ----------------
__global__ __launch_bounds__(256) void k_wprep4(const float* __restrict__ WA,  // 256x128
                                                const float* __restrict__ WB,  // 128x128
                                                const float* __restrict__ WC,  // 128x64
                                                const float* __restrict__ WD,  // 128x64
                                                bf16* __restrict__ wf0,        // 2 slots of 256*128
                                                bf16* __restrict__ wf1) {      // 2 slots of 128*64
    int y = blockIdx.y;
    const float* W = (y == 0) ? WA : (y == 1) ? WB : (y == 2) ? WC : WD;
    bf16* wf = (y == 0) ? wf0 : (y == 1) ? wf0 + 256 * 128 : (y == 2) ? wf1 : wf1 + 128 * 64;
    int K = (y == 0) ? 256 : 128;
    int F = (y <= 1) ? 128 : 64;
    int i = blockIdx.x * 256 + threadIdx.x;
    if (i < K * F) {
        int k = i / F, n = i % F;
        wf[((size_t)(k >> 3) * F + n) * 8 + (k & 7)] = (bf16)W[i];
    }
}

// ---------------- bf16 MFMA GEMM body: H[n x F] = X[n x K] @ W[K x F], H bf16 ----------------
// Fragment maps (16x16x32): A: m=l&15,k=(l>>4)*8+j ; B: n=l&15,k=(l>>4)*8+j ;
// D: n=l&15, m=(l>>4)*4+reg.
template <int K, int F, typename AT>
__device__ __forceinline__ void gemm_body(const AT* __restrict__ X,
                                          const bf16* __restrict__ wf,
                                          bf16* __restrict__ H, int n, int bx) {
    constexpr int NT = F / 16;
    int wave = threadIdx.x >> 6;
    int lane = threadIdx.x & 63;
    int lm = lane & 15;
    int lk = lane >> 4;
    int r0 = bx * 64 + wave * 16;

    int arow = r0 + lm;
    if (arow >= n) arow = n - 1;  // clamp (stores are guarded)
    const AT* xrow = X + (size_t)arow * K;

    f32x4 acc[NT] = {};

    for (int k0 = 0; k0 < K; k0 += 32) {
        bf16x8 af;
        if constexpr (std::is_same_v<AT, float>) {
            f32x4 a0 = *reinterpret_cast<const f32x4*>(xrow + k0 + lk * 8);
            f32x4 a1 = *reinterpret_cast<const f32x4*>(xrow + k0 + lk * 8 + 4);
            af[0] = (bf16)a0.x; af[1] = (bf16)a0.y; af[2] = (bf16)a0.z; af[3] = (bf16)a0.w;
            af[4] = (bf16)a1.x; af[5] = (bf16)a1.y; af[6] = (bf16)a1.z; af[7] = (bf16)a1.w;
        } else {
            af = *reinterpret_cast<const bf16x8*>(xrow + k0 + lk * 8);
        }
        const bf16* wbase = wf + ((size_t)(k0 / 8 + lk) * F) * 8;
        #pragma unroll
        for (int t = 0; t < NT; ++t) {
            bf16x8 bfg = *reinterpret_cast<const bf16x8*>(wbase + (t * 16 + lm) * 8);
            acc[t] = __builtin_amdgcn_mfma_f32_16x16x32_bf16(af, bfg, acc[t], 0, 0, 0);
        }
    }

    #pragma unroll
    for (int t = 0; t < NT; ++t) {
        #pragma unroll
        for (int i = 0; i < 4; ++i) {
            int gr = r0 + lk * 4 + i;
            if (gr < n) H[(size_t)gr * F + t * 16 + lm] = (bf16)acc[t][i];
        }
    }
}

static constexpr int GB = (NN + 63) / 64;  // 782 gemm blocks per graph

// layer 1: graph0 K=256 (x1 fp32), graph1 K=128 (x2 fp32), F=128
__global__ __launch_bounds__(256) void gemm_l1(const float* __restrict__ x1,
                                               const float* __restrict__ x2,
                                               const bf16* __restrict__ wf0,
                                               bf16* __restrict__ h) {
    int bx = blockIdx.x;
    if (bx < GB)
        gemm_body<256, 128, float>(x1, wf0, h, NN, bx);
    else
        gemm_body<128, 128, float>(x2, wf0 + 256 * 128, h + (size_t)NN * 128, NN, bx - GB);
}

// layer 2: both graphs K=128 -> F=64, A bf16
__global__ __launch_bounds__(256) void gemm_l2(const bf16* __restrict__ a,
                                               const bf16* __restrict__ wf1,
                                               bf16* __restrict__ h2) {
    int bx = blockIdx.x;
    int g = (bx >= GB);
    gemm_body<128, 64, bf16>(a + (size_t)g * NN * 128, wf1 + g * 128 * 64,
                             h2 + (size_t)g * NN * 64, NN, bx - g * GB);
}

// ---------------- aggregation F=128: wave per node, both graphs, ReLU, bf16 out ----------------
__global__ __launch_bounds__(256) void agg128_2(const bf16* __restrict__ hb,
                                                const int* __restrict__ row_off,
                                                const int2* __restrict__ pairb,
                                                const float* __restrict__ dinv,
                                                const float* __restrict__ biasA,
                                                const float* __restrict__ biasB,
                                                bf16* __restrict__ ab) {
    int wid = blockIdx.x * 4 + (threadIdx.x >> 6);
    if (wid >= 2 * NN) return;
    int g = (wid >= NN);
    int node = wid - g * NN;
    int lane = threadIdx.x & 63;

    const bf16* h = hb + (size_t)g * NN * 128;
    const int2* pair = pairb + (size_t)g * NE;
    const int* ro = row_off + g * (NN + 1);
    const float* bias = g ? biasB : biasA;

    int f = lane * 2;
    float di = dinv[g * NN + node];
    int beg = ro[node];
    int end = ro[node + 1];

    float a0 = 0.f, a1 = 0.f;

    int j = beg;
    for (; j + 3 < end; j += 4) {
        int2 p0 = pair[j], p1 = pair[j + 1], p2 = pair[j + 2], p3 = pair[j + 3];
        bf16x2 v0 = *reinterpret_cast<const bf16x2*>(&h[(size_t)p0.x * 128 + f]);
        bf16x2 v1 = *reinterpret_cast<const bf16x2*>(&h[(size_t)p1.x * 128 + f]);
        bf16x2 v2 = *reinterpret_cast<const bf16x2*>(&h[(size_t)p2.x * 128 + f]);
        bf16x2 v3 = *reinterpret_cast<const bf16x2*>(&h[(size_t)p3.x * 128 + f]);
        float c0 = __int_as_float(p0.y), c1 = __int_as_float(p1.y);
        float c2 = __int_as_float(p2.y), c3 = __int_as_float(p3.y);
        a0 = fmaf((float)v0[0], c0, a0); a1 = fmaf((float)v0[1], c0, a1);
        a0 = fmaf((float)v1[0], c1, a0); a1 = fmaf((float)v1[1], c1, a1);
        a0 = fmaf((float)v2[0], c2, a0); a1 = fmaf((float)v2[1], c2, a1);
        a0 = fmaf((float)v3[0], c3, a0); a1 = fmaf((float)v3[1], c3, a1);
    }
    for (; j < end; ++j) {
        int2 p = pair[j];
        float c = __int_as_float(p.y);
        bf16x2 v = *reinterpret_cast<const bf16x2*>(&h[(size_t)p.x * 128 + f]);
        a0 = fmaf((float)v[0], c, a0); a1 = fmaf((float)v[1], c, a1);
    }

    bf16x2 hv = *reinterpret_cast<const bf16x2*>(&h[(size_t)node * 128 + f]);
    float sc = di * di;
    a0 = fmaf((float)hv[0], sc, a0) + bias[f];
    a1 = fmaf((float)hv[1], sc, a1) + bias[f + 1];
    a0 = fmaxf(a0, 0.f);
    a1 = fmaxf(a1, 0.f);

    bf16x2 r;
    r[0] = (bf16)a0; r[1] = (bf16)a1;
    *reinterpret_cast<bf16x2*>(&ab[((size_t)g * NN + node) * 128 + f]) = r;
}

// ---------------- aggregation F=64: wave per node (2 edges/iter), both graphs, fp32 out ----------------
__global__ __launch_bounds__(256) void agg64_2(const bf16* __restrict__ h2b,
                                               const int* __restrict__ row_off,
                                               const int2* __restrict__ pairb,
                                               const float* __restrict__ dinv,
                                               const float* __restrict__ biasA,
                                               const float* __restrict__ biasB,
                                               float* __restrict__ outb) {
    int wid = blockIdx.x * 4 + (threadIdx.x >> 6);
    if (wid >= 2 * NN) return;
    int g = (wid >= NN);
    int node = wid - g * NN;
    int lane = threadIdx.x & 63;

    const bf16* h = h2b + (size_t)g * NN * 64;
    const int2* pair = pairb + (size_t)g * NE;
    const int* ro = row_off + g * (NN + 1);
    const float* bias = g ? biasB : biasA;
    float* out = outb + (size_t)g * NN * 64;

    int half = lane >> 5;
    int f = (lane & 31) * 2;
    float di = dinv[g * NN + node];
    int beg = ro[node];
    int end = ro[node + 1];

    float a0 = 0.f, a1 = 0.f;

    int j = beg;
    for (; j + 3 < end; j += 4) {
        int2 pA = pair[j + half], pB = pair[j + 2 + half];
        bf16x2 vA = *reinterpret_cast<const bf16x2*>(&h[(size_t)pA.x * 64 + f]);
        bf16x2 vB = *reinterpret_cast<const bf16x2*>(&h[(size_t)pB.x * 64 + f]);
        float cA = __int_as_float(pA.y), cB = __int_as_float(pB.y);
        a0 = fmaf((float)vA[0], cA, a0); a1 = fmaf((float)vA[1], cA, a1);
        a0 = fmaf((float)vB[0], cB, a0); a1 = fmaf((float)vB[1], cB, a1);
    }
    for (; j + 1 < end; j += 2) {
        int2 p = pair[j + half];
        float c = __int_as_float(p.y);
        bf16x2 v = *reinterpret_cast<const bf16x2*>(&h[(size_t)p.x * 64 + f]);
        a0 = fmaf((float)v[0], c, a0); a1 = fmaf((float)v[1], c, a1);
    }
    if (j < end && half == 0) {
        int2 p = pair[j];
        float c = __int_as_float(p.y);
        bf16x2 v = *reinterpret_cast<const bf16x2*>(&h[(size_t)p.x * 64 + f]);
        a0 = fmaf((float)v[0], c, a0); a1 = fmaf((float)v[1], c, a1);
    }

    a0 += __shfl_xor(a0, 32);
    a1 += __shfl_xor(a1, 32);

    bf16x2 hv = *reinterpret_cast<const bf16x2*>(&h[(size_t)node * 64 + f]);
    float sc = di * di;
    a0 = fmaf((float)hv[0], sc, a0) + bias[f];
    a1 = fmaf((float)hv[1], sc, a1) + bias[f + 1];

    if (half == 0) {
        out[(size_t)node * 64 + f] = a0;
        out[(size_t)node * 64 + f + 1] = a1;
    }
}

extern "C" void kernel_launch(void* const* d_in, const int* in_sizes, int n_in,
                              void* d_out, int out_size, void* d_ws, size_t ws_size,
                              hipStream_t stream) {
    const float* x1 = (const float*)d_in[0];
    const int* ei1 = (const int*)d_in[1];
    const float* x2 = (const float*)d_in[2];
    const int* ei2 = (const int*)d_in[3];
    const float* W1_0 = (const float*)d_in[4];
    const float* b1_0 = (const float*)d_in[5];
    const float* W1_1 = (const float*)d_in[6];
    const float* b1_1 = (const float*)d_in[7];
    const float* W2_0 = (const float*)d_in[8];
    const float* b2_0 = (const float*)d_in[9];
    const float* W2_1 = (const float*)d_in[10];
    const float* b2_1 = (const float*)d_in[11];

    float* out = (float*)d_out;  // [2][NN][64] concatenated

    char* ws = (char*)d_ws;
    size_t off = 0;
    auto alloc = [&](size_t bytes) {
        size_t o = off;
        off = (off + bytes + 255) & ~(size_t)255;
        return o;
    };
    bf16* h = (bf16*)(ws + alloc((size_t)2 * NN * 128 * 2));   // layer1 out / layer2 out (reused)
    bf16* a = (bf16*)(ws + alloc((size_t)2 * NN * 128 * 2));   // layer1 agg out
    int2* pair = (int2*)(ws + alloc((size_t)2 * NE * 8));
    int* row_off = (int*)(ws + alloc((size_t)2 * (NN + 1) * 4));
    int* deg = (int*)(ws + alloc((size_t)2 * NN * 4));
    int* poscur = (int*)(ws + alloc((size_t)2 * NN * 4));
    float* dinv = (float*)(ws + alloc((size_t)2 * NN * 4));
    int* bsum = (int*)(ws + alloc((size_t)2 * NBLK * 4));
    int* boff = (int*)(ws + alloc((size_t)2 * NBLK * 4));
    bf16* wf0 = (bf16*)(ws + alloc((size_t)2 * 256 * 128 * 2));
    bf16* wf1 = (bf16*)(ws + alloc((size_t)2 * 128 * 64 * 2));

    const int* srcA = ei1, *dstA = ei1 + NE;
    const int* srcB = ei2, *dstB = ei2 + NE;

    hipMemsetAsync(deg, 0, (size_t)2 * NN * 4, stream);
    k_count_deg2<<<(2 * NE + 255) / 256, 256, 0, stream>>>(dstA, dstB, deg);
    k_blocksum2<<<dim3(NBLK, 2), 256, 0, stream>>>(deg, bsum);
    k_scan_aux2<<<2, 256, 0, stream>>>(bsum, boff, row_off);
    k_scan_final2<<<dim3(NBLK, 2), 256, 0, stream>>>(deg, boff, row_off, poscur, dinv);
    k_fill2<<<(2 * NE + 255) / 256, 256, 0, stream>>>(srcA, dstA, srcB, dstB, poscur, dinv, pair);
    k_wprep4<<<dim3(128, 4), 256, 0, stream>>>(W1_0, W2_0, W1_1, W2_1, wf0, wf1);

    gemm_l1<<<2 * GB, 256, 0, stream>>>(x1, x2, wf0, h);
    agg128_2<<<(2 * NN + 3) / 4, 256, 0, stream>>>(h, row_off, pair, dinv, b1_0, b2_0, a);
    gemm_l2<<<2 * GB, 256, 0, stream>>>(a, wf1, h);
    agg64_2<<<(2 * NN + 3) / 4, 256, 0, stream>>>(h, row_off, pair, dinv, b1_1, b2_1, out);
}

// Round 6
// 255.096 us; speedup vs baseline: 1.7748x; 1.1271x over previous
//
#include <hip/hip_runtime.h>
#include <hip/hip_bf16.h>
#include <cstdint>
#include <type_traits>

static constexpr int NN = 50000;   // nodes per graph
static constexpr int NE = 600000;  // edges per graph
static constexpr int NBLK = (NN + 255) / 256;  // 196 scan blocks per graph (<= 256)
static constexpr int NB = (NN + 255) / 256;    // 196 dst-buckets (256 nodes each)
static constexpr int CHUNK = 4096;
static constexpr int NCH = (NE + CHUNK - 1) / CHUNK;  // 147 binning chunks per graph

typedef __bf16 bf16;
typedef __attribute__((ext_vector_type(2))) __bf16 bf16x2;
typedef __attribute__((ext_vector_type(8))) __bf16 bf16x8;
typedef __attribute__((ext_vector_type(4))) float f32x4;

// ---------------- degree count, both graphs ----------------
__global__ __launch_bounds__(256) void k_count_deg2(const int* __restrict__ dstA,
                                                    const int* __restrict__ dstB,
                                                    int* __restrict__ deg) {
    int i = blockIdx.x * 256 + threadIdx.x;
    if (i < NE) atomicAdd(&deg[dstA[i]], 1);
    else if (i < 2 * NE) atomicAdd(&deg[NN + dstB[i - NE]], 1);
}

// ---------------- exclusive scan (3 kernels), both graphs via grid.y ----------------
__global__ __launch_bounds__(256) void k_blocksum2(const int* __restrict__ deg,
                                                   int* __restrict__ bsum) {
    __shared__ int s[256];
    int g = blockIdx.y;
    int tid = threadIdx.x;
    int i = blockIdx.x * 256 + tid;
    s[tid] = (i < NN) ? deg[g * NN + i] : 0;
    __syncthreads();
    for (int off = 128; off > 0; off >>= 1) {
        if (tid < off) s[tid] += s[tid + off];
        __syncthreads();
    }
    if (tid == 0) bsum[g * NBLK + blockIdx.x] = s[0];
}

__global__ __launch_bounds__(256) void k_scan_aux2(const int* __restrict__ bsum,
                                                   int* __restrict__ boff,
                                                   int* __restrict__ row_off) {
    __shared__ int s[256];
    int g = blockIdx.x;
    int tid = threadIdx.x;
    int v = (tid < NBLK) ? bsum[g * NBLK + tid] : 0;
    s[tid] = v;
    __syncthreads();
    for (int off = 1; off < 256; off <<= 1) {
        int t = (tid >= off) ? s[tid - off] : 0;
        __syncthreads();
        s[tid] += t;
        __syncthreads();
    }
    if (tid < NBLK) boff[g * NBLK + tid] = s[tid] - v;           // exclusive block offsets
    if (tid == NBLK - 1) row_off[g * (NN + 1) + NN] = s[tid];    // total (= NE)
}

// writes row_off, bucket cursors (bucket start = row_off[b*256]) and dinv
__global__ __launch_bounds__(256) void k_scan_final2(const int* __restrict__ deg,
                                                     const int* __restrict__ boff,
                                                     int* __restrict__ row_off,
                                                     int* __restrict__ bcur,
                                                     float* __restrict__ dinv) {
    __shared__ int s[256];
    int g = blockIdx.y;
    int tid = threadIdx.x;
    int i = blockIdx.x * 256 + tid;
    int v = (i < NN) ? deg[g * NN + i] : 0;
    s[tid] = v;
    __syncthreads();
    for (int off = 1; off < 256; off <<= 1) {
        int t = (tid >= off) ? s[tid - off] : 0;
        __syncthreads();
        s[tid] += t;
        __syncthreads();
    }
    if (i < NN) {
        int excl = boff[g * NBLK + blockIdx.x] + s[tid] - v;
        row_off[g * (NN + 1) + i] = excl;
        if ((i & 255) == 0) bcur[g * NB + (i >> 8)] = excl;
        dinv[g * NN + i] = rsqrtf((float)v + 1.0f);
    }
}

// ---------------- binned fill phase A: histogram + sub-range scatter of (src,dst) ----------------
__global__ __launch_bounds__(256) void k_binA(const int* __restrict__ srcA,
                                              const int* __restrict__ dstA,
                                              const int* __restrict__ srcB,
                                              const int* __restrict__ dstB,
                                              int* __restrict__ bcur,
                                              int2* __restrict__ stg) {
    __shared__ int cnt[NB];
    __shared__ int ibase[NB];
    int g = blockIdx.y;
    const int* src = g ? srcB : srcA;
    const int* dst = g ? dstB : dstA;
    int tid = threadIdx.x;
    int c0 = blockIdx.x * CHUNK;
    if (tid < NB) cnt[tid] = 0;
    __syncthreads();
    #pragma unroll
    for (int it = 0; it < CHUNK / 256; ++it) {
        int e = c0 + it * 256 + tid;
        if (e < NE) atomicAdd(&cnt[dst[e] >> 8], 1);
    }
    __syncthreads();
    if (tid < NB) {
        int c = cnt[tid];
        ibase[tid] = c ? atomicAdd(&bcur[g * NB + tid], c) : 0;
        cnt[tid] = 0;
    }
    __syncthreads();
    #pragma unroll
    for (int it = 0; it < CHUNK / 256; ++it) {
        int e = c0 + it * 256 + tid;
        if (e < NE) {
            int s = src[e], d = dst[e];
            int b = d >> 8;
            int p = atomicAdd(&cnt[b], 1);
            stg[(size_t)g * NE + ibase[b] + p] = make_int2(s, d);
        }
    }
}

// ---------------- binned fill phase B: bucket -> exact CSR position (LDS cursors) ----------------
__global__ __launch_bounds__(256) void k_binB(const int2* __restrict__ stg,
                                              const int* __restrict__ row_off,
                                              const float* __restrict__ dinv,
                                              int2* __restrict__ pair) {
    __shared__ int lcur[256];
    __shared__ float ldv[256];
    int g = blockIdx.y;
    int b = blockIdx.x;
    int tid = threadIdx.x;
    int node0 = b << 8;
    int nnod = min(256, NN - node0);
    const int* ro = row_off + g * (NN + 1);
    if (tid < nnod) {
        lcur[tid] = ro[node0 + tid];
        ldv[tid] = dinv[(size_t)g * NN + node0 + tid];
    }
    __syncthreads();
    int r0 = ro[node0];
    int r1 = ro[node0 + nnod];
    for (int j = r0 + tid; j < r1; j += 256) {
        int2 sd = stg[(size_t)g * NE + j];
        int rel = sd.y - node0;
        int pos = atomicAdd(&lcur[rel], 1);
        float cf = dinv[(size_t)g * NN + sd.x] * ldv[rel];
        pair[(size_t)g * NE + pos] = make_int2(sd.x, __float_as_int(cf));
    }
}

// ---------------- W prep: fp32 [K][F] -> fragment-order bf16 wf[k/8][n][8], 4 jobs ----------------
__global__ __launch_bounds__(256) void k_wprep4(const float* __restrict__ WA,  // 256x128
                                                const float* __restrict__ WB,  // 128x128
                                                const float* __restrict__ WC,  // 128x64
                                                const float* __restrict__ WD,  // 128x64
                                                bf16* __restrict__ wf0,        // 2 slots of 256*128
                                                bf16* __restrict__ wf1) {      // 2 slots of 128*64
    int y = blockIdx.y;
    const float* W = (y == 0) ? WA : (y == 1) ? WB : (y == 2) ? WC : WD;
    bf16* wf = (y == 0) ? wf0 : (y == 1) ? wf0 + 256 * 128 : (y == 2) ? wf1 : wf1 + 128 * 64;
    int K = (y == 0) ? 256 : 128;
    int F = (y <= 1) ? 128 : 64;
    int i = blockIdx.x * 256 + threadIdx.x;
    if (i < K * F) {
        int k = i / F, n = i % F;
        wf[((size_t)(k >> 3) * F + n) * 8 + (k & 7)] = (bf16)W[i];
    }
}

// ---------------- bf16 MFMA GEMM body ----------------
// Fragment maps (16x16x32): A: m=l&15,k=(l>>4)*8+j ; B: n=l&15,k=(l>>4)*8+j ;
// D: n=l&15, m=(l>>4)*4+reg.
template <int K, int F, typename AT>
__device__ __forceinline__ void gemm_body(const AT* __restrict__ X,
                                          const bf16* __restrict__ wf,
                                          bf16* __restrict__ H, int n, int bx) {
    constexpr int NT = F / 16;
    int wave = threadIdx.x >> 6;
    int lane = threadIdx.x & 63;
    int lm = lane & 15;
    int lk = lane >> 4;
    int r0 = bx * 64 + wave * 16;

    int arow = r0 + lm;
    if (arow >= n) arow = n - 1;  // clamp (stores are guarded)
    const AT* xrow = X + (size_t)arow * K;

    f32x4 acc[NT] = {};

    for (int k0 = 0; k0 < K; k0 += 32) {
        bf16x8 af;
        if constexpr (std::is_same_v<AT, float>) {
            f32x4 a0 = *reinterpret_cast<const f32x4*>(xrow + k0 + lk * 8);
            f32x4 a1 = *reinterpret_cast<const f32x4*>(xrow + k0 + lk * 8 + 4);
            af[0] = (bf16)a0.x; af[1] = (bf16)a0.y; af[2] = (bf16)a0.z; af[3] = (bf16)a0.w;
            af[4] = (bf16)a1.x; af[5] = (bf16)a1.y; af[6] = (bf16)a1.z; af[7] = (bf16)a1.w;
        } else {
            af = *reinterpret_cast<const bf16x8*>(xrow + k0 + lk * 8);
        }
        const bf16* wbase = wf + ((size_t)(k0 / 8 + lk) * F) * 8;
        #pragma unroll
        for (int t = 0; t < NT; ++t) {
            bf16x8 bfg = *reinterpret_cast<const bf16x8*>(wbase + (t * 16 + lm) * 8);
            acc[t] = __builtin_amdgcn_mfma_f32_16x16x32_bf16(af, bfg, acc[t], 0, 0, 0);
        }
    }

    #pragma unroll
    for (int t = 0; t < NT; ++t) {
        #pragma unroll
        for (int i = 0; i < 4; ++i) {
            int gr = r0 + lk * 4 + i;
            if (gr < n) H[(size_t)gr * F + t * 16 + lm] = (bf16)acc[t][i];
        }
    }
}

static constexpr int GB = (NN + 63) / 64;  // 782 gemm blocks per graph

// layer 1: graph0 K=256 (x1 fp32), graph1 K=128 (x2 fp32), F=128
__global__ __launch_bounds__(256) void gemm_l1(const float* __restrict__ x1,
                                               const float* __restrict__ x2,
                                               const bf16* __restrict__ wf0,
                                               bf16* __restrict__ h) {
    int bx = blockIdx.x;
    if (bx < GB)
        gemm_body<256, 128, float>(x1, wf0, h, NN, bx);
    else
        gemm_body<128, 128, float>(x2, wf0 + 256 * 128, h + (size_t)NN * 128, NN, bx - GB);
}

// layer 2: both graphs K=128 -> F=64, A bf16
__global__ __launch_bounds__(256) void gemm_l2(const bf16* __restrict__ a,
                                               const bf16* __restrict__ wf1,
                                               bf16* __restrict__ h2) {
    int bx = blockIdx.x;
    int g = (bx >= GB);
    gemm_body<128, 64, bf16>(a + (size_t)g * NN * 128, wf1 + g * 128 * 64,
                             h2 + (size_t)g * NN * 64, NN, bx - g * GB);
}

// ---------------- aggregation F=128: wave per node, both graphs, ReLU, bf16 out ----------------
__global__ __launch_bounds__(256) void agg128_2(const bf16* __restrict__ hb,
                                                const int* __restrict__ row_off,
                                                const int2* __restrict__ pairb,
                                                const float* __restrict__ dinv,
                                                const float* __restrict__ biasA,
                                                const float* __restrict__ biasB,
                                                bf16* __restrict__ ab) {
    int wid = blockIdx.x * 4 + (threadIdx.x >> 6);
    if (wid >= 2 * NN) return;
    int g = (wid >= NN);
    int node = wid - g * NN;
    int lane = threadIdx.x & 63;

    const bf16* h = hb + (size_t)g * NN * 128;
    const int2* pair = pairb + (size_t)g * NE;
    const int* ro = row_off + g * (NN + 1);
    const float* bias = g ? biasB : biasA;

    int f = lane * 2;
    float di = dinv[g * NN + node];
    int beg = ro[node];
    int end = ro[node + 1];

    float a0 = 0.f, a1 = 0.f;

    int j = beg;
    for (; j + 3 < end; j += 4) {
        int2 p0 = pair[j], p1 = pair[j + 1], p2 = pair[j + 2], p3 = pair[j + 3];
        bf16x2 v0 = *reinterpret_cast<const bf16x2*>(&h[(size_t)p0.x * 128 + f]);
        bf16x2 v1 = *reinterpret_cast<const bf16x2*>(&h[(size_t)p1.x * 128 + f]);
        bf16x2 v2 = *reinterpret_cast<const bf16x2*>(&h[(size_t)p2.x * 128 + f]);
        bf16x2 v3 = *reinterpret_cast<const bf16x2*>(&h[(size_t)p3.x * 128 + f]);
        float c0 = __int_as_float(p0.y), c1 = __int_as_float(p1.y);
        float c2 = __int_as_float(p2.y), c3 = __int_as_float(p3.y);
        a0 = fmaf((float)v0[0], c0, a0); a1 = fmaf((float)v0[1], c0, a1);
        a0 = fmaf((float)v1[0], c1, a0); a1 = fmaf((float)v1[1], c1, a1);
        a0 = fmaf((float)v2[0], c2, a0); a1 = fmaf((float)v2[1], c2, a1);
        a0 = fmaf((float)v3[0], c3, a0); a1 = fmaf((float)v3[1], c3, a1);
    }
    for (; j < end; ++j) {
        int2 p = pair[j];
        float c = __int_as_float(p.y);
        bf16x2 v = *reinterpret_cast<const bf16x2*>(&h[(size_t)p.x * 128 + f]);
        a0 = fmaf((float)v[0], c, a0); a1 = fmaf((float)v[1], c, a1);
    }

    bf16x2 hv = *reinterpret_cast<const bf16x2*>(&h[(size_t)node * 128 + f]);
    float sc = di * di;
    a0 = fmaf((float)hv[0], sc, a0) + bias[f];
    a1 = fmaf((float)hv[1], sc, a1) + bias[f + 1];
    a0 = fmaxf(a0, 0.f);
    a1 = fmaxf(a1, 0.f);

    bf16x2 r;
    r[0] = (bf16)a0; r[1] = (bf16)a1;
    *reinterpret_cast<bf16x2*>(&ab[((size_t)g * NN + node) * 128 + f]) = r;
}

// ---------------- aggregation F=64: wave per node (2 edges/iter), both graphs, fp32 out ----------------
__global__ __launch_bounds__(256) void agg64_2(const bf16* __restrict__ h2b,
                                               const int* __restrict__ row_off,
                                               const int2* __restrict__ pairb,
                                               const float* __restrict__ dinv,
                                               const float* __restrict__ biasA,
                                               const float* __restrict__ biasB,
                                               float* __restrict__ outb) {
    int wid = blockIdx.x * 4 + (threadIdx.x >> 6);
    if (wid >= 2 * NN) return;
    int g = (wid >= NN);
    int node = wid - g * NN;
    int lane = threadIdx.x & 63;

    const bf16* h = h2b + (size_t)g * NN * 64;
    const int2* pair = pairb + (size_t)g * NE;
    const int* ro = row_off + g * (NN + 1);
    const float* bias = g ? biasB : biasA;
    float* out = outb + (size_t)g * NN * 64;

    int half = lane >> 5;
    int f = (lane & 31) * 2;
    float di = dinv[(size_t)g * NN + node];
    int beg = ro[node];
    int end = ro[node + 1];

    float a0 = 0.f, a1 = 0.f;

    int j = beg;
    for (; j + 3 < end; j += 4) {
        int2 pA = pair[j + half], pB = pair[j + 2 + half];
        bf16x2 vA = *reinterpret_cast<const bf16x2*>(&h[(size_t)pA.x * 64 + f]);
        bf16x2 vB = *reinterpret_cast<const bf16x2*>(&h[(size_t)pB.x * 64 + f]);
        float cA = __int_as_float(pA.y), cB = __int_as_float(pB.y);
        a0 = fmaf((float)vA[0], cA, a0); a1 = fmaf((float)vA[1], cA, a1);
        a0 = fmaf((float)vB[0], cB, a0); a1 = fmaf((float)vB[1], cB, a1);
    }
    for (; j + 1 < end; j += 2) {
        int2 p = pair[j + half];
        float c = __int_as_float(p.y);
        bf16x2 v = *reinterpret_cast<const bf16x2*>(&h[(size_t)p.x * 64 + f]);
        a0 = fmaf((float)v[0], c, a0); a1 = fmaf((float)v[1], c, a1);
    }
    if (j < end && half == 0) {
        int2 p = pair[j];
        float c = __int_as_float(p.y);
        bf16x2 v = *reinterpret_cast<const bf16x2*>(&h[(size_t)p.x * 64 + f]);
        a0 = fmaf((float)v[0], c, a0); a1 = fmaf((float)v[1], c, a1);
    }

    a0 += __shfl_xor(a0, 32);
    a1 += __shfl_xor(a1, 32);

    bf16x2 hv = *reinterpret_cast<const bf16x2*>(&h[(size_t)node * 64 + f]);
    float sc = di * di;
    a0 = fmaf((float)hv[0], sc, a0) + bias[f];
    a1 = fmaf((float)hv[1], sc, a1) + bias[f + 1];

    if (half == 0) {
        out[(size_t)node * 64 + f] = a0;
        out[(size_t)node * 64 + f + 1] = a1;
    }
}

extern "C" void kernel_launch(void* const* d_in, const int* in_sizes, int n_in,
                              void* d_out, int out_size, void* d_ws, size_t ws_size,
                              hipStream_t stream) {
    const float* x1 = (const float*)d_in[0];
    const int* ei1 = (const int*)d_in[1];
    const float* x2 = (const float*)d_in[2];
    const int* ei2 = (const int*)d_in[3];
    const float* W1_0 = (const float*)d_in[4];
    const float* b1_0 = (const float*)d_in[5];
    const float* W1_1 = (const float*)d_in[6];
    const float* b1_1 = (const float*)d_in[7];
    const float* W2_0 = (const float*)d_in[8];
    const float* b2_0 = (const float*)d_in[9];
    const float* W2_1 = (const float*)d_in[10];
    const float* b2_1 = (const float*)d_in[11];

    float* out = (float*)d_out;  // [2][NN][64] concatenated

    char* ws = (char*)d_ws;
    size_t off = 0;
    auto alloc = [&](size_t bytes) {
        size_t o = off;
        off = (off + bytes + 255) & ~(size_t)255;
        return o;
    };
    // region1 hosts stg -> h -> h2 (lifetimes strictly serialized on the stream:
    // binB consumes stg before gemm_l1 writes h; h is dead before gemm_l2 writes h2)
    char* region1 = ws + alloc((size_t)2 * NN * 128 * 2);      // 25.6 MB
    int2* stg = (int2*)region1;                                // 9.6 MB alias
    bf16* h = (bf16*)region1;                                  // 25.6 MB alias
    bf16* h2 = (bf16*)region1;                                 // 12.8 MB alias
    bf16* a = (bf16*)(ws + alloc((size_t)2 * NN * 128 * 2));   // layer-1 agg out
    int2* pair = (int2*)(ws + alloc((size_t)2 * NE * 8));      // CSR (src, coef)
    int* row_off = (int*)(ws + alloc((size_t)2 * (NN + 1) * 4));
    int* deg = (int*)(ws + alloc((size_t)2 * NN * 4));
    int* bcur = (int*)(ws + alloc((size_t)2 * NB * 4));
    float* dinv = (float*)(ws + alloc((size_t)2 * NN * 4));
    int* bsum = (int*)(ws + alloc((size_t)2 * NBLK * 4));
    int* boff = (int*)(ws + alloc((size_t)2 * NBLK * 4));
    bf16* wf0 = (bf16*)(ws + alloc((size_t)2 * 256 * 128 * 2));
    bf16* wf1 = (bf16*)(ws + alloc((size_t)2 * 128 * 64 * 2));

    const int* srcA = ei1, *dstA = ei1 + NE;
    const int* srcB = ei2, *dstB = ei2 + NE;

    hipMemsetAsync(deg, 0, (size_t)2 * NN * 4, stream);
    k_count_deg2<<<(2 * NE + 255) / 256, 256, 0, stream>>>(dstA, dstB, deg);
    k_blocksum2<<<dim3(NBLK, 2), 256, 0, stream>>>(deg, bsum);
    k_scan_aux2<<<2, 256, 0, stream>>>(bsum, boff, row_off);
    k_scan_final2<<<dim3(NBLK, 2), 256, 0, stream>>>(deg, boff, row_off, bcur, dinv);
    k_binA<<<dim3(NCH, 2), 256, 0, stream>>>(srcA, dstA, srcB, dstB, bcur, stg);
    k_binB<<<dim3(NB, 2), 256, 0, stream>>>(stg, row_off, dinv, pair);
    k_wprep4<<<dim3(128, 4), 256, 0, stream>>>(W1_0, W2_0, W1_1, W2_1, wf0, wf1);

    gemm_l1<<<2 * GB, 256, 0, stream>>>(x1, x2, wf0, h);
    agg128_2<<<(2 * NN + 3) / 4, 256, 0, stream>>>(h, row_off, pair, dinv, b1_0, b2_0, a);
    gemm_l2<<<2 * GB, 256, 0, stream>>>(a, wf1, h2);
    agg64_2<<<(2 * NN + 3) / 4, 256, 0, stream>>>(h2, row_off, pair, dinv, b1_1, b2_1, out);
}

// Round 8
// 236.352 us; speedup vs baseline: 1.9156x; 1.0793x over previous
//
#include <hip/hip_runtime.h>
#include <hip/hip_bf16.h>
#include <cstdint>
#include <type_traits>

static constexpr int NN = 50000;   // nodes per graph
static constexpr int NE = 600000;  // edges per graph
static constexpr int NBLK = (NN + 255) / 256;  // 196 scan blocks per graph (<= 256)
static constexpr int NB = (NN + 255) / 256;    // 196 dst-buckets (256 nodes each)
static constexpr int CHUNK = 4096;
static constexpr int NCH = (NE + CHUNK - 1) / CHUNK;  // 147 binning chunks per graph
static constexpr int CAP = 4096;  // per-bucket staging capacity (mean 3061, ~18 sigma)

typedef __bf16 bf16;
typedef __attribute__((ext_vector_type(2))) __bf16 bf16x2;
typedef __attribute__((ext_vector_type(8))) __bf16 bf16x8;
typedef __attribute__((ext_vector_type(4))) float f32x4;

// ---------------- bucket cursor init: bucketcur[B] = B*CAP (absolute stg index) ----------------
__global__ __launch_bounds__(256) void k_init(int* __restrict__ bucketcur) {
    int i = blockIdx.x * 256 + threadIdx.x;
    if (i < 2 * NB) bucketcur[i] = i * CAP;
}

// ---------------- binA: LDS-stage chunk, histogram (+global deg), scatter to bucket regions ----
__global__ __launch_bounds__(256) void k_binA(const int* __restrict__ srcA,
                                              const int* __restrict__ dstA,
                                              const int* __restrict__ srcB,
                                              const int* __restrict__ dstB,
                                              int* __restrict__ deg,
                                              int* __restrict__ bucketcur,
                                              int2* __restrict__ stg) {
    __shared__ int2 ed[CHUNK];   // 32 KB staged (src,dst)
    __shared__ int cnt[NB];
    __shared__ int ibase[NB];
    int g = blockIdx.y;
    const int* src = g ? srcB : srcA;
    const int* dst = g ? dstB : dstA;
    int tid = threadIdx.x;
    int c0 = blockIdx.x * CHUNK;
    if (tid < NB) cnt[tid] = 0;
    __syncthreads();
    #pragma unroll
    for (int it = 0; it < CHUNK / 256; ++it) {
        int e = c0 + it * 256 + tid;
        if (e < NE) {
            int s = src[e], d = dst[e];
            ed[it * 256 + tid] = make_int2(s, d);
            atomicAdd(&cnt[d >> 8], 1);
            atomicAdd(&deg[g * NN + d], 1);   // replaces k_count_deg2
        }
    }
    __syncthreads();
    if (tid < NB) {
        int c = cnt[tid];
        ibase[tid] = c ? atomicAdd(&bucketcur[g * NB + tid], c) : 0;
        cnt[tid] = 0;
    }
    __syncthreads();
    #pragma unroll
    for (int it = 0; it < CHUNK / 256; ++it) {
        int e = c0 + it * 256 + tid;
        if (e < NE) {
            int2 sd = ed[it * 256 + tid];
            int b = sd.y >> 8;
            int p = atomicAdd(&cnt[b], 1);
            stg[(size_t)ibase[b] + p] = sd;   // ibase is absolute
        }
    }
}

// ---------------- exclusive scan (3 kernels), both graphs via grid.y ----------------
__global__ __launch_bounds__(256) void k_blocksum2(const int* __restrict__ deg,
                                                   int* __restrict__ bsum) {
    __shared__ int s[256];
    int g = blockIdx.y;
    int tid = threadIdx.x;
    int i = blockIdx.x * 256 + tid;
    s[tid] = (i < NN) ? deg[g * NN + i] : 0;
    __syncthreads();
    for (int off = 128; off > 0; off >>= 1) {
        if (tid < off) s[tid] += s[tid + off];
        __syncthreads();
    }
    if (tid == 0) bsum[g * NBLK + blockIdx.x] = s[0];
}

__global__ __launch_bounds__(256) void k_scan_aux2(const int* __restrict__ bsum,
                                                   int* __restrict__ boff,
                                                   int* __restrict__ row_off) {
    __shared__ int s[256];
    int g = blockIdx.x;
    int tid = threadIdx.x;
    int v = (tid < NBLK) ? bsum[g * NBLK + tid] : 0;
    s[tid] = v;
    __syncthreads();
    for (int off = 1; off < 256; off <<= 1) {
        int t = (tid >= off) ? s[tid - off] : 0;
        __syncthreads();
        s[tid] += t;
        __syncthreads();
    }
    if (tid < NBLK) boff[g * NBLK + tid] = s[tid] - v;           // exclusive block offsets
    if (tid == NBLK - 1) row_off[g * (NN + 1) + NN] = s[tid];    // total (= NE)
}

// writes row_off and dinv
__global__ __launch_bounds__(256) void k_scan_final2(const int* __restrict__ deg,
                                                     const int* __restrict__ boff,
                                                     int* __restrict__ row_off,
                                                     float* __restrict__ dinv) {
    __shared__ int s[256];
    int g = blockIdx.y;
    int tid = threadIdx.x;
    int i = blockIdx.x * 256 + tid;
    int v = (i < NN) ? deg[g * NN + i] : 0;
    s[tid] = v;
    __syncthreads();
    for (int off = 1; off < 256; off <<= 1) {
        int t = (tid >= off) ? s[tid - off] : 0;
        __syncthreads();
        s[tid] += t;
        __syncthreads();
    }
    if (i < NN) {
        row_off[g * (NN + 1) + i] = boff[g * NBLK + blockIdx.x] + s[tid] - v;
        dinv[g * NN + i] = rsqrtf((float)v + 1.0f);
    }
}

// ---------------- binB: bucket region -> exact CSR position (LDS cursors) + coef ----------------
__global__ __launch_bounds__(256) void k_binB(const int2* __restrict__ stg,
                                              const int* __restrict__ bucketcur,
                                              const int* __restrict__ row_off,
                                              const float* __restrict__ dinv,
                                              int2* __restrict__ pair) {
    __shared__ int lcur[256];
    __shared__ float ldv[256];
    int g = blockIdx.y;
    int b = blockIdx.x;
    int B = g * NB + b;
    int tid = threadIdx.x;
    int node0 = b << 8;
    int nnod = min(256, NN - node0);
    const int* ro = row_off + g * (NN + 1);
    if (tid < nnod) {
        lcur[tid] = ro[node0 + tid];
        ldv[tid] = dinv[(size_t)g * NN + node0 + tid];
    }
    __syncthreads();
    int count = bucketcur[B] - B * CAP;
    const int2* s0 = stg + (size_t)B * CAP;
    for (int j = tid; j < count; j += 256) {
        int2 sd = s0[j];
        int rel = sd.y - node0;
        int pos = atomicAdd(&lcur[rel], 1);
        float cf = dinv[(size_t)g * NN + sd.x] * ldv[rel];
        pair[(size_t)g * NE + pos] = make_int2(sd.x, __float_as_int(cf));
    }
}

// ---------------- W prep: fp32 [K][F] -> fragment-order bf16 wf[k/8][n][8], 4 jobs ----------------
__global__ __launch_bounds__(256) void k_wprep4(const float* __restrict__ WA,  // 256x128
                                                const float* __restrict__ WB,  // 128x128
                                                const float* __restrict__ WC,  // 128x64
                                                const float* __restrict__ WD,  // 128x64
                                                bf16* __restrict__ wf0,        // 2 slots of 256*128
                                                bf16* __restrict__ wf1) {      // 2 slots of 128*64
    int y = blockIdx.y;
    const float* W = (y == 0) ? WA : (y == 1) ? WB : (y == 2) ? WC : WD;
    bf16* wf = (y == 0) ? wf0 : (y == 1) ? wf0 + 256 * 128 : (y == 2) ? wf1 : wf1 + 128 * 64;
    int K = (y == 0) ? 256 : 128;
    int F = (y <= 1) ? 128 : 64;
    int i = blockIdx.x * 256 + threadIdx.x;
    if (i < K * F) {
        int k = i / F, n = i % F;
        wf[((size_t)(k >> 3) * F + n) * 8 + (k & 7)] = (bf16)W[i];
    }
}

// ---------------- bf16 MFMA GEMM body ----------------
// Fragment maps (16x16x32): A: m=l&15,k=(l>>4)*8+j ; B: n=l&15,k=(l>>4)*8+j ;
// D: n=l&15, m=(l>>4)*4+reg.
template <int K, int F, typename AT>
__device__ __forceinline__ void gemm_body(const AT* __restrict__ X,
                                          const bf16* __restrict__ wf,
                                          bf16* __restrict__ H, int n, int bx) {
    constexpr int NT = F / 16;
    int wave = threadIdx.x >> 6;
    int lane = threadIdx.x & 63;
    int lm = lane & 15;
    int lk = lane >> 4;
    int r0 = bx * 64 + wave * 16;

    int arow = r0 + lm;
    if (arow >= n) arow = n - 1;  // clamp (stores are guarded)
    const AT* xrow = X + (size_t)arow * K;

    f32x4 acc[NT] = {};

    for (int k0 = 0; k0 < K; k0 += 32) {
        bf16x8 af;
        if constexpr (std::is_same_v<AT, float>) {
            f32x4 a0 = *reinterpret_cast<const f32x4*>(xrow + k0 + lk * 8);
            f32x4 a1 = *reinterpret_cast<const f32x4*>(xrow + k0 + lk * 8 + 4);
            af[0] = (bf16)a0.x; af[1] = (bf16)a0.y; af[2] = (bf16)a0.z; af[3] = (bf16)a0.w;
            af[4] = (bf16)a1.x; af[5] = (bf16)a1.y; af[6] = (bf16)a1.z; af[7] = (bf16)a1.w;
        } else {
            af = *reinterpret_cast<const bf16x8*>(xrow + k0 + lk * 8);
        }
        const bf16* wbase = wf + ((size_t)(k0 / 8 + lk) * F) * 8;
        #pragma unroll
        for (int t = 0; t < NT; ++t) {
            bf16x8 bfg = *reinterpret_cast<const bf16x8*>(wbase + (t * 16 + lm) * 8);
            acc[t] = __builtin_amdgcn_mfma_f32_16x16x32_bf16(af, bfg, acc[t], 0, 0, 0);
        }
    }

    #pragma unroll
    for (int t = 0; t < NT; ++t) {
        #pragma unroll
        for (int i = 0; i < 4; ++i) {
            int gr = r0 + lk * 4 + i;
            if (gr < n) H[(size_t)gr * F + t * 16 + lm] = (bf16)acc[t][i];
        }
    }
}

static constexpr int GB = (NN + 63) / 64;  // 782 gemm blocks per graph

// layer 1: graph0 K=256 (x1 fp32), graph1 K=128 (x2 fp32), F=128
__global__ __launch_bounds__(256) void gemm_l1(const float* __restrict__ x1,
                                               const float* __restrict__ x2,
                                               const bf16* __restrict__ wf0,
                                               bf16* __restrict__ h) {
    int bx = blockIdx.x;
    if (bx < GB)
        gemm_body<256, 128, float>(x1, wf0, h, NN, bx);
    else
        gemm_body<128, 128, float>(x2, wf0 + 256 * 128, h + (size_t)NN * 128, NN, bx - GB);
}

// layer 2: both graphs K=128 -> F=64, A bf16
__global__ __launch_bounds__(256) void gemm_l2(const bf16* __restrict__ a,
                                               const bf16* __restrict__ wf1,
                                               bf16* __restrict__ h2) {
    int bx = blockIdx.x;
    int g = (bx >= GB);
    gemm_body<128, 64, bf16>(a + (size_t)g * NN * 128, wf1 + g * 128 * 64,
                             h2 + (size_t)g * NN * 64, NN, bx - g * GB);
}

// ---------------- aggregation F=128: wave per node, int4 pair loads, 8-edge unroll ----------------
__global__ __launch_bounds__(256) void agg128_2(const bf16* __restrict__ hb,
                                                const int* __restrict__ row_off,
                                                const int2* __restrict__ pairb,
                                                const float* __restrict__ dinv,
                                                const float* __restrict__ biasA,
                                                const float* __restrict__ biasB,
                                                bf16* __restrict__ ab) {
    int wid = blockIdx.x * 4 + (threadIdx.x >> 6);
    if (wid >= 2 * NN) return;
    int g = (wid >= NN);
    int node = wid - g * NN;
    int lane = threadIdx.x & 63;

    const bf16* h = hb + (size_t)g * NN * 128;
    const int2* pair = pairb + (size_t)g * NE;
    const int* ro = row_off + g * (NN + 1);
    const float* bias = g ? biasB : biasA;

    int f = lane * 2;
    float di = dinv[g * NN + node];
    int beg = ro[node];
    int end = ro[node + 1];

    float a0 = 0.f, a1 = 0.f;

    auto edge1 = [&](int2 p) {
        float c = __int_as_float(p.y);
        bf16x2 v = *reinterpret_cast<const bf16x2*>(&h[(size_t)p.x * 128 + f]);
        a0 = fmaf((float)v[0], c, a0); a1 = fmaf((float)v[1], c, a1);
    };
    auto edge2 = [&](int4 q) {  // two edges in one aligned 16B load
        float cA = __int_as_float(q.y), cB = __int_as_float(q.w);
        bf16x2 vA = *reinterpret_cast<const bf16x2*>(&h[(size_t)q.x * 128 + f]);
        bf16x2 vB = *reinterpret_cast<const bf16x2*>(&h[(size_t)q.z * 128 + f]);
        a0 = fmaf((float)vA[0], cA, a0); a1 = fmaf((float)vA[1], cA, a1);
        a0 = fmaf((float)vB[0], cB, a0); a1 = fmaf((float)vB[1], cB, a1);
    };

    int j = beg;
    if ((j & 1) && j < end) { edge1(pair[j]); ++j; }  // align to 16B
    for (; j + 7 < end; j += 8) {
        int4 q0 = *reinterpret_cast<const int4*>(&pair[j]);
        int4 q1 = *reinterpret_cast<const int4*>(&pair[j + 2]);
        int4 q2 = *reinterpret_cast<const int4*>(&pair[j + 4]);
        int4 q3 = *reinterpret_cast<const int4*>(&pair[j + 6]);
        edge2(q0); edge2(q1); edge2(q2); edge2(q3);
    }
    for (; j + 1 < end; j += 2) {
        int4 q = *reinterpret_cast<const int4*>(&pair[j]);
        edge2(q);
    }
    if (j < end) edge1(pair[j]);

    bf16x2 hv = *reinterpret_cast<const bf16x2*>(&h[(size_t)node * 128 + f]);
    float sc = di * di;
    a0 = fmaf((float)hv[0], sc, a0) + bias[f];
    a1 = fmaf((float)hv[1], sc, a1) + bias[f + 1];
    a0 = fmaxf(a0, 0.f);
    a1 = fmaxf(a1, 0.f);

    bf16x2 r;
    r[0] = (bf16)a0; r[1] = (bf16)a1;
    *reinterpret_cast<bf16x2*>(&ab[((size_t)g * NN + node) * 128 + f]) = r;
}

// ---------------- aggregation F=64: wave per node (2 edges in parallel, 8-unrolled) ----------------
__global__ __launch_bounds__(256) void agg64_2(const bf16* __restrict__ h2b,
                                               const int* __restrict__ row_off,
                                               const int2* __restrict__ pairb,
                                               const float* __restrict__ dinv,
                                               const float* __restrict__ biasA,
                                               const float* __restrict__ biasB,
                                               float* __restrict__ outb) {
    int wid = blockIdx.x * 4 + (threadIdx.x >> 6);
    if (wid >= 2 * NN) return;
    int g = (wid >= NN);
    int node = wid - g * NN;
    int lane = threadIdx.x & 63;

    const bf16* h = h2b + (size_t)g * NN * 64;
    const int2* pair = pairb + (size_t)g * NE;
    const int* ro = row_off + g * (NN + 1);
    const float* bias = g ? biasB : biasA;
    float* out = outb + (size_t)g * NN * 64;

    int half = lane >> 5;
    int f = (lane & 31) * 2;
    float di = dinv[(size_t)g * NN + node];
    int beg = ro[node];
    int end = ro[node + 1];

    float a0 = 0.f, a1 = 0.f;

    auto edge = [&](int2 p) {
        float c = __int_as_float(p.y);
        bf16x2 v = *reinterpret_cast<const bf16x2*>(&h[(size_t)p.x * 64 + f]);
        a0 = fmaf((float)v[0], c, a0); a1 = fmaf((float)v[1], c, a1);
    };

    int j = beg;
    for (; j + 7 < end; j += 8) {
        int2 p0 = pair[j + half], p1 = pair[j + 2 + half];
        int2 p2 = pair[j + 4 + half], p3 = pair[j + 6 + half];
        edge(p0); edge(p1); edge(p2); edge(p3);
    }
    for (; j + 1 < end; j += 2) edge(pair[j + half]);
    if (j < end && half == 0) edge(pair[j]);

    a0 += __shfl_xor(a0, 32);
    a1 += __shfl_xor(a1, 32);

    bf16x2 hv = *reinterpret_cast<const bf16x2*>(&h[(size_t)node * 64 + f]);
    float sc = di * di;
    a0 = fmaf((float)hv[0], sc, a0) + bias[f];
    a1 = fmaf((float)hv[1], sc, a1) + bias[f + 1];

    if (half == 0) {
        out[(size_t)node * 64 + f] = a0;
        out[(size_t)node * 64 + f + 1] = a1;
    }
}

extern "C" void kernel_launch(void* const* d_in, const int* in_sizes, int n_in,
                              void* d_out, int out_size, void* d_ws, size_t ws_size,
                              hipStream_t stream) {
    const float* x1 = (const float*)d_in[0];
    const int* ei1 = (const int*)d_in[1];
    const float* x2 = (const float*)d_in[2];
    const int* ei2 = (const int*)d_in[3];
    const float* W1_0 = (const float*)d_in[4];
    const float* b1_0 = (const float*)d_in[5];
    const float* W1_1 = (const float*)d_in[6];
    const float* b1_1 = (const float*)d_in[7];
    const float* W2_0 = (const float*)d_in[8];
    const float* b2_0 = (const float*)d_in[9];
    const float* W2_1 = (const float*)d_in[10];
    const float* b2_1 = (const float*)d_in[11];

    float* out = (float*)d_out;  // [2][NN][64] concatenated

    char* ws = (char*)d_ws;
    size_t off = 0;
    auto alloc = [&](size_t bytes) {
        size_t o = off;
        off = (off + bytes + 255) & ~(size_t)255;
        return o;
    };
    // h: live gemm_l1 -> agg128. region2: stg (dead after binB) then h2 (written by gemm_l2).
    bf16* h = (bf16*)(ws + alloc((size_t)2 * NN * 128 * 2));       // 25.6 MB
    size_t r2 = (size_t)2 * NB * CAP * 8;                          // 12.85 MB (>= h2's 12.8)
    char* region2 = ws + alloc(r2);
    int2* stg = (int2*)region2;
    bf16* h2 = (bf16*)region2;
    bf16* a = (bf16*)(ws + alloc((size_t)2 * NN * 128 * 2));       // 25.6 MB
    int2* pair = (int2*)(ws + alloc((size_t)2 * NE * 8));          // 9.6 MB
    int* row_off = (int*)(ws + alloc((size_t)2 * (NN + 1) * 4));
    int* deg = (int*)(ws + alloc((size_t)2 * NN * 4));
    float* dinv = (float*)(ws + alloc((size_t)2 * NN * 4));
    int* bucketcur = (int*)(ws + alloc((size_t)2 * NB * 4));
    int* bsum = (int*)(ws + alloc((size_t)2 * NBLK * 4));
    int* boff = (int*)(ws + alloc((size_t)2 * NBLK * 4));
    bf16* wf0 = (bf16*)(ws + alloc((size_t)2 * 256 * 128 * 2));
    bf16* wf1 = (bf16*)(ws + alloc((size_t)2 * 128 * 64 * 2));

    const int* srcA = ei1, *dstA = ei1 + NE;
    const int* srcB = ei2, *dstB = ei2 + NE;

    hipMemsetAsync(deg, 0, (size_t)2 * NN * 4, stream);
    k_init<<<(2 * NB + 255) / 256, 256, 0, stream>>>(bucketcur);
    k_wprep4<<<dim3(128, 4), 256, 0, stream>>>(W1_0, W2_0, W1_1, W2_1, wf0, wf1);
    k_binA<<<dim3(NCH, 2), 256, 0, stream>>>(srcA, dstA, srcB, dstB, deg, bucketcur, stg);
    k_blocksum2<<<dim3(NBLK, 2), 256, 0, stream>>>(deg, bsum);
    k_scan_aux2<<<2, 256, 0, stream>>>(bsum, boff, row_off);
    k_scan_final2<<<dim3(NBLK, 2), 256, 0, stream>>>(deg, boff, row_off, dinv);
    k_binB<<<dim3(NB, 2), 256, 0, stream>>>(stg, bucketcur, row_off, dinv, pair);

    gemm_l1<<<2 * GB, 256, 0, stream>>>(x1, x2, wf0, h);
    agg128_2<<<(2 * NN + 3) / 4, 256, 0, stream>>>(h, row_off, pair, dinv, b1_0, b2_0, a);
    gemm_l2<<<2 * GB, 256, 0, stream>>>(a, wf1, h2);
    agg64_2<<<(2 * NN + 3) / 4, 256, 0, stream>>>(h2, row_off, pair, dinv, b1_1, b2_1, out);
}

// Round 9
// 201.717 us; speedup vs baseline: 2.2445x; 1.1717x over previous
//
#include <hip/hip_runtime.h>
#include <hip/hip_bf16.h>
#include <cstdint>
#include <type_traits>

static constexpr int NN = 50000;   // nodes per graph
static constexpr int NE = 600000;  // edges per graph
static constexpr int NB = (NN + 255) / 256;    // 196 dst-buckets (256 nodes each)
static constexpr int CHUNK = 1024;
static constexpr int NCH = (NE + CHUNK - 1) / CHUNK;  // 586 binning chunks per graph
static constexpr int CAP = 4096;  // per-bucket staging capacity (mean 3072, ~18 sigma)

typedef __bf16 bf16;
typedef __attribute__((ext_vector_type(2))) __bf16 bf16x2;
typedef __attribute__((ext_vector_type(8))) __bf16 bf16x8;
typedef __attribute__((ext_vector_type(4))) float f32x4;

// ---------------- init: bucket cursors (absolute stg index) + row_off totals ----------------
__global__ __launch_bounds__(256) void k_init(int* __restrict__ bucketcur,
                                              int* __restrict__ row_off) {
    int i = blockIdx.x * 256 + threadIdx.x;
    if (i < 2 * NB) bucketcur[i] = i * CAP;
    if (i < 2) row_off[i * (NN + 1) + NN] = NE;
}

// ---------------- binA: per-chunk LDS histogram -> bucket-region scatter of (src,dst) --------
// 1172 lightweight blocks (1.6 KB LDS) for occupancy; src/dst re-read (L2-hot).
__global__ __launch_bounds__(256) void k_binA(const int* __restrict__ srcA,
                                              const int* __restrict__ dstA,
                                              const int* __restrict__ srcB,
                                              const int* __restrict__ dstB,
                                              int* __restrict__ bucketcur,
                                              int2* __restrict__ stg) {
    __shared__ int cnt[NB];
    __shared__ int ibase[NB];
    int g = blockIdx.y;
    const int* src = g ? srcB : srcA;
    const int* dst = g ? dstB : dstA;
    int tid = threadIdx.x;
    int c0 = blockIdx.x * CHUNK;
    if (tid < NB) cnt[tid] = 0;
    __syncthreads();
    #pragma unroll
    for (int it = 0; it < CHUNK / 256; ++it) {
        int e = c0 + it * 256 + tid;
        if (e < NE) atomicAdd(&cnt[dst[e] >> 8], 1);
    }
    __syncthreads();
    if (tid < NB) {
        int c = cnt[tid];
        ibase[tid] = c ? atomicAdd(&bucketcur[g * NB + tid], c) : 0;
        cnt[tid] = 0;
    }
    __syncthreads();
    #pragma unroll
    for (int it = 0; it < CHUNK / 256; ++it) {
        int e = c0 + it * 256 + tid;
        if (e < NE) {
            int s = src[e], d = dst[e];
            int b = d >> 8;
            int p = atomicAdd(&cnt[b], 1);
            stg[(size_t)ibase[b] + p] = make_int2(s, d);  // ibase is absolute
        }
    }
}

// ---------------- bucket-total exclusive scan (1 block per graph) ----------------
__global__ __launch_bounds__(256) void k_bucket_scan(const int* __restrict__ bucketcur,
                                                     int* __restrict__ bucket_base) {
    __shared__ int s[256];
    int g = blockIdx.x;
    int tid = threadIdx.x;
    int B = g * NB + tid;
    int v = (tid < NB) ? bucketcur[B] - B * CAP : 0;
    s[tid] = v;
    __syncthreads();
    for (int off = 1; off < 256; off <<= 1) {
        int t = (tid >= off) ? s[tid - off] : 0;
        __syncthreads();
        s[tid] += t;
        __syncthreads();
    }
    if (tid < NB) bucket_base[B] = s[tid] - v;  // exclusive
}

// ---------------- binB1: per-bucket node histogram -> row_off slice + dinv ----------------
__global__ __launch_bounds__(256) void k_binB1(const int2* __restrict__ stg,
                                               const int* __restrict__ bucketcur,
                                               const int* __restrict__ bucket_base,
                                               int* __restrict__ row_off,
                                               float* __restrict__ dinv) {
    __shared__ int cnt[256];
    __shared__ int s[256];
    int g = blockIdx.y;
    int b = blockIdx.x;
    int B = g * NB + b;
    int tid = threadIdx.x;
    int node0 = b << 8;
    int nnod = min(256, NN - node0);
    cnt[tid] = 0;
    __syncthreads();
    int count = bucketcur[B] - B * CAP;
    const int2* s0 = stg + (size_t)B * CAP;
    for (int j = tid; j < count; j += 256)
        atomicAdd(&cnt[s0[j].y - node0], 1);
    __syncthreads();
    int v = cnt[tid];
    s[tid] = v;
    __syncthreads();
    for (int off = 1; off < 256; off <<= 1) {
        int t = (tid >= off) ? s[tid - off] : 0;
        __syncthreads();
        s[tid] += t;
        __syncthreads();
    }
    if (tid < nnod) {
        row_off[g * (NN + 1) + node0 + tid] = bucket_base[B] + s[tid] - v;
        dinv[(size_t)g * NN + node0 + tid] = rsqrtf((float)v + 1.0f);
    }
}

// ---------------- binB2: bucket region -> exact CSR position (LDS cursors) + coef ----------
__global__ __launch_bounds__(256) void k_binB2(const int2* __restrict__ stg,
                                               const int* __restrict__ bucketcur,
                                               const int* __restrict__ row_off,
                                               const float* __restrict__ dinv,
                                               int2* __restrict__ pair) {
    __shared__ int lcur[256];
    __shared__ float ldv[256];
    int g = blockIdx.y;
    int b = blockIdx.x;
    int B = g * NB + b;
    int tid = threadIdx.x;
    int node0 = b << 8;
    int nnod = min(256, NN - node0);
    const int* ro = row_off + g * (NN + 1);
    if (tid < nnod) {
        lcur[tid] = ro[node0 + tid];
        ldv[tid] = dinv[(size_t)g * NN + node0 + tid];
    }
    __syncthreads();
    int count = bucketcur[B] - B * CAP;
    const int2* s0 = stg + (size_t)B * CAP;
    for (int j = tid; j < count; j += 256) {
        int2 sd = s0[j];
        int rel = sd.y - node0;
        int pos = atomicAdd(&lcur[rel], 1);
        float cf = dinv[(size_t)g * NN + sd.x] * ldv[rel];
        pair[(size_t)g * NE + pos] = make_int2(sd.x, __float_as_int(cf));
    }
}

// ---------------- W prep: fp32 [K][F] -> fragment-order bf16 wf[k/8][n][8], 4 jobs ----------------
__global__ __launch_bounds__(256) void k_wprep4(const float* __restrict__ WA,  // 256x128
                                                const float* __restrict__ WB,  // 128x128
                                                const float* __restrict__ WC,  // 128x64
                                                const float* __restrict__ WD,  // 128x64
                                                bf16* __restrict__ wf0,        // 2 slots of 256*128
                                                bf16* __restrict__ wf1) {      // 2 slots of 128*64
    int y = blockIdx.y;
    const float* W = (y == 0) ? WA : (y == 1) ? WB : (y == 2) ? WC : WD;
    bf16* wf = (y == 0) ? wf0 : (y == 1) ? wf0 + 256 * 128 : (y == 2) ? wf1 : wf1 + 128 * 64;
    int K = (y == 0) ? 256 : 128;
    int F = (y <= 1) ? 128 : 64;
    int i = blockIdx.x * 256 + threadIdx.x;
    if (i < K * F) {
        int k = i / F, n = i % F;
        wf[((size_t)(k >> 3) * F + n) * 8 + (k & 7)] = (bf16)W[i];
    }
}

// ---------------- bf16 MFMA GEMM body ----------------
// Fragment maps (16x16x32): A: m=l&15,k=(l>>4)*8+j ; B: n=l&15,k=(l>>4)*8+j ;
// D: n=l&15, m=(l>>4)*4+reg.
template <int K, int F, typename AT>
__device__ __forceinline__ void gemm_body(const AT* __restrict__ X,
                                          const bf16* __restrict__ wf,
                                          bf16* __restrict__ H, int n, int bx) {
    constexpr int NT = F / 16;
    int wave = threadIdx.x >> 6;
    int lane = threadIdx.x & 63;
    int lm = lane & 15;
    int lk = lane >> 4;
    int r0 = bx * 64 + wave * 16;

    int arow = r0 + lm;
    if (arow >= n) arow = n - 1;  // clamp (stores are guarded)
    const AT* xrow = X + (size_t)arow * K;

    f32x4 acc[NT] = {};

    for (int k0 = 0; k0 < K; k0 += 32) {
        bf16x8 af;
        if constexpr (std::is_same_v<AT, float>) {
            f32x4 a0 = *reinterpret_cast<const f32x4*>(xrow + k0 + lk * 8);
            f32x4 a1 = *reinterpret_cast<const f32x4*>(xrow + k0 + lk * 8 + 4);
            af[0] = (bf16)a0.x; af[1] = (bf16)a0.y; af[2] = (bf16)a0.z; af[3] = (bf16)a0.w;
            af[4] = (bf16)a1.x; af[5] = (bf16)a1.y; af[6] = (bf16)a1.z; af[7] = (bf16)a1.w;
        } else {
            af = *reinterpret_cast<const bf16x8*>(xrow + k0 + lk * 8);
        }
        const bf16* wbase = wf + ((size_t)(k0 / 8 + lk) * F) * 8;
        #pragma unroll
        for (int t = 0; t < NT; ++t) {
            bf16x8 bfg = *reinterpret_cast<const bf16x8*>(wbase + (t * 16 + lm) * 8);
            acc[t] = __builtin_amdgcn_mfma_f32_16x16x32_bf16(af, bfg, acc[t], 0, 0, 0);
        }
    }

    #pragma unroll
    for (int t = 0; t < NT; ++t) {
        #pragma unroll
        for (int i = 0; i < 4; ++i) {
            int gr = r0 + lk * 4 + i;
            if (gr < n) H[(size_t)gr * F + t * 16 + lm] = (bf16)acc[t][i];
        }
    }
}

static constexpr int GB = (NN + 63) / 64;  // 782 gemm blocks per graph

// layer 1: graph0 K=256 (x1 fp32), graph1 K=128 (x2 fp32), F=128
__global__ __launch_bounds__(256) void gemm_l1(const float* __restrict__ x1,
                                               const float* __restrict__ x2,
                                               const bf16* __restrict__ wf0,
                                               bf16* __restrict__ h) {
    int bx = blockIdx.x;
    if (bx < GB)
        gemm_body<256, 128, float>(x1, wf0, h, NN, bx);
    else
        gemm_body<128, 128, float>(x2, wf0 + 256 * 128, h + (size_t)NN * 128, NN, bx - GB);
}

// layer 2: both graphs K=128 -> F=64, A bf16
__global__ __launch_bounds__(256) void gemm_l2(const bf16* __restrict__ a,
                                               const bf16* __restrict__ wf1,
                                               bf16* __restrict__ h2) {
    int bx = blockIdx.x;
    int g = (bx >= GB);
    gemm_body<128, 64, bf16>(a + (size_t)g * NN * 128, wf1 + g * 128 * 64,
                             h2 + (size_t)g * NN * 64, NN, bx - g * GB);
}

// ---------------- aggregation F=128: wave per node, int4 pair loads, 8-edge unroll ----------------
__global__ __launch_bounds__(256) void agg128_2(const bf16* __restrict__ hb,
                                                const int* __restrict__ row_off,
                                                const int2* __restrict__ pairb,
                                                const float* __restrict__ dinv,
                                                const float* __restrict__ biasA,
                                                const float* __restrict__ biasB,
                                                bf16* __restrict__ ab) {
    int wid = blockIdx.x * 4 + (threadIdx.x >> 6);
    if (wid >= 2 * NN) return;
    int g = (wid >= NN);
    int node = wid - g * NN;
    int lane = threadIdx.x & 63;

    const bf16* h = hb + (size_t)g * NN * 128;
    const int2* pair = pairb + (size_t)g * NE;
    const int* ro = row_off + g * (NN + 1);
    const float* bias = g ? biasB : biasA;

    int f = lane * 2;
    float di = dinv[g * NN + node];
    int beg = ro[node];
    int end = ro[node + 1];

    float a0 = 0.f, a1 = 0.f;

    auto edge1 = [&](int2 p) {
        float c = __int_as_float(p.y);
        bf16x2 v = *reinterpret_cast<const bf16x2*>(&h[(size_t)p.x * 128 + f]);
        a0 = fmaf((float)v[0], c, a0); a1 = fmaf((float)v[1], c, a1);
    };
    auto edge2 = [&](int4 q) {  // two edges in one aligned 16B load
        float cA = __int_as_float(q.y), cB = __int_as_float(q.w);
        bf16x2 vA = *reinterpret_cast<const bf16x2*>(&h[(size_t)q.x * 128 + f]);
        bf16x2 vB = *reinterpret_cast<const bf16x2*>(&h[(size_t)q.z * 128 + f]);
        a0 = fmaf((float)vA[0], cA, a0); a1 = fmaf((float)vA[1], cA, a1);
        a0 = fmaf((float)vB[0], cB, a0); a1 = fmaf((float)vB[1], cB, a1);
    };

    int j = beg;
    if ((j & 1) && j < end) { edge1(pair[j]); ++j; }  // align to 16B
    for (; j + 7 < end; j += 8) {
        int4 q0 = *reinterpret_cast<const int4*>(&pair[j]);
        int4 q1 = *reinterpret_cast<const int4*>(&pair[j + 2]);
        int4 q2 = *reinterpret_cast<const int4*>(&pair[j + 4]);
        int4 q3 = *reinterpret_cast<const int4*>(&pair[j + 6]);
        edge2(q0); edge2(q1); edge2(q2); edge2(q3);
    }
    for (; j + 1 < end; j += 2) {
        int4 q = *reinterpret_cast<const int4*>(&pair[j]);
        edge2(q);
    }
    if (j < end) edge1(pair[j]);

    bf16x2 hv = *reinterpret_cast<const bf16x2*>(&h[(size_t)node * 128 + f]);
    float sc = di * di;
    a0 = fmaf((float)hv[0], sc, a0) + bias[f];
    a1 = fmaf((float)hv[1], sc, a1) + bias[f + 1];
    a0 = fmaxf(a0, 0.f);
    a1 = fmaxf(a1, 0.f);

    bf16x2 r;
    r[0] = (bf16)a0; r[1] = (bf16)a1;
    *reinterpret_cast<bf16x2*>(&ab[((size_t)g * NN + node) * 128 + f]) = r;
}

// ---------------- aggregation F=64: wave per node (2 edges in parallel, 8-unrolled) ----------------
__global__ __launch_bounds__(256) void agg64_2(const bf16* __restrict__ h2b,
                                               const int* __restrict__ row_off,
                                               const int2* __restrict__ pairb,
                                               const float* __restrict__ dinv,
                                               const float* __restrict__ biasA,
                                               const float* __restrict__ biasB,
                                               float* __restrict__ outb) {
    int wid = blockIdx.x * 4 + (threadIdx.x >> 6);
    if (wid >= 2 * NN) return;
    int g = (wid >= NN);
    int node = wid - g * NN;
    int lane = threadIdx.x & 63;

    const bf16* h = h2b + (size_t)g * NN * 64;
    const int2* pair = pairb + (size_t)g * NE;
    const int* ro = row_off + g * (NN + 1);
    const float* bias = g ? biasB : biasA;
    float* out = outb + (size_t)g * NN * 64;

    int half = lane >> 5;
    int f = (lane & 31) * 2;
    float di = dinv[(size_t)g * NN + node];
    int beg = ro[node];
    int end = ro[node + 1];

    float a0 = 0.f, a1 = 0.f;

    auto edge = [&](int2 p) {
        float c = __int_as_float(p.y);
        bf16x2 v = *reinterpret_cast<const bf16x2*>(&h[(size_t)p.x * 64 + f]);
        a0 = fmaf((float)v[0], c, a0); a1 = fmaf((float)v[1], c, a1);
    };

    int j = beg;
    for (; j + 7 < end; j += 8) {
        int2 p0 = pair[j + half], p1 = pair[j + 2 + half];
        int2 p2 = pair[j + 4 + half], p3 = pair[j + 6 + half];
        edge(p0); edge(p1); edge(p2); edge(p3);
    }
    for (; j + 1 < end; j += 2) edge(pair[j + half]);
    if (j < end && half == 0) edge(pair[j]);

    a0 += __shfl_xor(a0, 32);
    a1 += __shfl_xor(a1, 32);

    bf16x2 hv = *reinterpret_cast<const bf16x2*>(&h[(size_t)node * 64 + f]);
    float sc = di * di;
    a0 = fmaf((float)hv[0], sc, a0) + bias[f];
    a1 = fmaf((float)hv[1], sc, a1) + bias[f + 1];

    if (half == 0) {
        out[(size_t)node * 64 + f] = a0;
        out[(size_t)node * 64 + f + 1] = a1;
    }
}

extern "C" void kernel_launch(void* const* d_in, const int* in_sizes, int n_in,
                              void* d_out, int out_size, void* d_ws, size_t ws_size,
                              hipStream_t stream) {
    const float* x1 = (const float*)d_in[0];
    const int* ei1 = (const int*)d_in[1];
    const float* x2 = (const float*)d_in[2];
    const int* ei2 = (const int*)d_in[3];
    const float* W1_0 = (const float*)d_in[4];
    const float* b1_0 = (const float*)d_in[5];
    const float* W1_1 = (const float*)d_in[6];
    const float* b1_1 = (const float*)d_in[7];
    const float* W2_0 = (const float*)d_in[8];
    const float* b2_0 = (const float*)d_in[9];
    const float* W2_1 = (const float*)d_in[10];
    const float* b2_1 = (const float*)d_in[11];

    float* out = (float*)d_out;  // [2][NN][64] concatenated

    char* ws = (char*)d_ws;
    size_t off = 0;
    auto alloc = [&](size_t bytes) {
        size_t o = off;
        off = (off + bytes + 255) & ~(size_t)255;
        return o;
    };
    // h: live gemm_l1 -> agg128. region2: stg (dead after binB2) then h2 (written by gemm_l2).
    bf16* h = (bf16*)(ws + alloc((size_t)2 * NN * 128 * 2));       // 25.6 MB
    size_t r2 = (size_t)2 * NB * CAP * 8;                          // 12.85 MB (>= h2's 12.8)
    char* region2 = ws + alloc(r2);
    int2* stg = (int2*)region2;
    bf16* h2 = (bf16*)region2;
    bf16* a = (bf16*)(ws + alloc((size_t)2 * NN * 128 * 2));       // 25.6 MB
    int2* pair = (int2*)(ws + alloc((size_t)2 * NE * 8));          // 9.6 MB
    int* row_off = (int*)(ws + alloc((size_t)2 * (NN + 1) * 4));
    float* dinv = (float*)(ws + alloc((size_t)2 * NN * 4));
    int* bucketcur = (int*)(ws + alloc((size_t)2 * NB * 4));
    int* bucket_base = (int*)(ws + alloc((size_t)2 * NB * 4));
    bf16* wf0 = (bf16*)(ws + alloc((size_t)2 * 256 * 128 * 2));
    bf16* wf1 = (bf16*)(ws + alloc((size_t)2 * 128 * 64 * 2));

    const int* srcA = ei1, *dstA = ei1 + NE;
    const int* srcB = ei2, *dstB = ei2 + NE;

    k_init<<<(2 * NB + 255) / 256, 256, 0, stream>>>(bucketcur, row_off);
    k_wprep4<<<dim3(128, 4), 256, 0, stream>>>(W1_0, W2_0, W1_1, W2_1, wf0, wf1);
    k_binA<<<dim3(NCH, 2), 256, 0, stream>>>(srcA, dstA, srcB, dstB, bucketcur, stg);
    k_bucket_scan<<<2, 256, 0, stream>>>(bucketcur, bucket_base);
    k_binB1<<<dim3(NB, 2), 256, 0, stream>>>(stg, bucketcur, bucket_base, row_off, dinv);
    k_binB2<<<dim3(NB, 2), 256, 0, stream>>>(stg, bucketcur, row_off, dinv, pair);

    gemm_l1<<<2 * GB, 256, 0, stream>>>(x1, x2, wf0, h);
    agg128_2<<<(2 * NN + 3) / 4, 256, 0, stream>>>(h, row_off, pair, dinv, b1_0, b2_0, a);
    gemm_l2<<<2 * GB, 256, 0, stream>>>(a, wf1, h2);
    agg64_2<<<(2 * NN + 3) / 4, 256, 0, stream>>>(h2, row_off, pair, dinv, b1_1, b2_1, out);
}